// Round 6
// baseline (780.953 us; speedup 1.0000x reference)
//
#include <hip/hip_runtime.h>
#include <cstddef>
#include <cstdint>

typedef unsigned short u16;
typedef unsigned int   u32;
typedef __bf16  bf16x8 __attribute__((ext_vector_type(8)));
typedef float   f32x4  __attribute__((ext_vector_type(4)));

#define DEV __device__ __forceinline__

DEV float b2f(u16 u) { union { u32 i; float f; } c; c.i = ((u32)u) << 16; return c.f; }
DEV u16 f2b(float x) { union { float f; u32 i; } c; c.f = x; u32 b = c.i;
                       return (u16)((b + 0x7FFFu + ((b >> 16) & 1u)) >> 16); }
DEV float sigm(float x)  { return 1.0f / (1.0f + __expf(-x)); }
DEV float tanh_(float x) { return 1.0f - 2.0f / (1.0f + __expf(2.0f * x)); }
DEV float gelu_(float x) { return 0.5f * x * (1.0f + erff(x * 0.70710678118654752f)); }

DEV void u4tof8(uint4 v, float* f) {
    f[0] = b2f((u16)(v.x & 0xFFFF)); f[1] = b2f((u16)(v.x >> 16));
    f[2] = b2f((u16)(v.y & 0xFFFF)); f[3] = b2f((u16)(v.y >> 16));
    f[4] = b2f((u16)(v.z & 0xFFFF)); f[5] = b2f((u16)(v.z >> 16));
    f[6] = b2f((u16)(v.w & 0xFFFF)); f[7] = b2f((u16)(v.w >> 16));
}
DEV uint4 f8tou4(const float* f) {
    uint4 v;
    v.x = (u32)f2b(f[0]) | ((u32)f2b(f[1]) << 16);
    v.y = (u32)f2b(f[2]) | ((u32)f2b(f[3]) << 16);
    v.z = (u32)f2b(f[4]) | ((u32)f2b(f[5]) << 16);
    v.w = (u32)f2b(f[6]) | ((u32)f2b(f[7]) << 16);
    return v;
}

// ---- workspace byte offsets; total 118,546,432 B (fits: 144,113,664 proven) ----
#define OB_X     0ull            // x  [40000][128] bf16
#define OB_FB    10240000ull     // fb [20000][128] bf16
#define OB_PRU   15360000ull     // PrU [40000][256] bf16 (= x@Wr^T + urb)
#define OB_H     35840000ull     // h   [40000][256] bf16
#define OB_UH    56320000ull     // Uh  [40000][256] bf16 ; nei overlays after loop
#define OB_SH    76800000ull     // sumh  [40000][256] bf16
#define OB_SGH   97280000ull     // sumgh [40000][256] bf16
#define OB_BZ    117760000ull    // BzT [256][384] bf16 : Wz[:, :111]|pad|Wz[:,111:]
#define OB_BH    117956608ull    // BhT [256][384] bf16
#define OB_BU    118153216ull    // BuT [256][256] bf16
#define OB_BR    118284288ull    // BrT [256][128] bf16 (Wr, K-pad)
#define OB_BO    118349824ull    // BoT [256][384] bf16 : Wo[:, :98]|pad|Wo[:,98:]
#define WS_BYTES 118546432ull

// ---------------------------------------------------------------------------
// Weight repack -> [N][K] bf16. Grid 384x256.
__global__ __launch_bounds__(256) void k_repack(
    const float* __restrict__ Wz, const float* __restrict__ Wr,
    const float* __restrict__ Ur, const float* __restrict__ Wh,
    const float* __restrict__ Wo,
    u16* __restrict__ BzT, u16* __restrict__ BhT, u16* __restrict__ BuT,
    u16* __restrict__ BrT, u16* __restrict__ BoT) {
    int idx = blockIdx.x * 256 + threadIdx.x;   // 0..98303
    {
        int n = idx / 384, k = idx % 384;
        float vz, vh, vo;
        if (k < 111)      { vz = Wz[n * 367 + k];      vh = Wh[n * 367 + k]; }
        else if (k < 128) { vz = 0.0f;                 vh = 0.0f; }
        else              { vz = Wz[n * 367 + k - 17]; vh = Wh[n * 367 + k - 17]; }
        if (k < 98)       vo = Wo[n * 354 + k];
        else if (k < 128) vo = 0.0f;
        else              vo = Wo[n * 354 + k - 30];
        BzT[idx] = f2b(vz); BhT[idx] = f2b(vh); BoT[idx] = f2b(vo);
    }
    if (idx < 65536) BuT[idx] = f2b(Ur[idx]);
    if (idx < 32768) {
        int n = idx >> 7, k = idx & 127;
        BrT[idx] = f2b(k < 111 ? Wr[n * 111 + k] : 0.0f);
    }
}

// x[e][c] (bf16, [40000][128], zero pad). Grid 20000x256 (2 edges/block).
__global__ __launch_bounds__(256) void k_build_x(const float* __restrict__ fnode,
                                                 const float* __restrict__ fmess,
                                                 u16* __restrict__ x) {
    int e = (blockIdx.x << 1) + (threadIdx.x >> 7);
    int c = threadIdx.x & 127;
    int src = (int)fmess[(size_t)e * 15];
    float v = 0.0f;
    if (c < 98)       v = fnode[(size_t)src * 98 + c];
    else if (c < 111) v = fmess[(size_t)e * 15 + 2 + (c - 98)];
    x[(size_t)e * 128 + c] = f2b(v);
}

// fb [20000][128] bf16 zero-padded. Grid 10000x256.
__global__ __launch_bounds__(256) void k_build_fb(const float* __restrict__ fnode,
                                                  u16* __restrict__ fb) {
    int idx = blockIdx.x * 256 + threadIdx.x;
    int n = idx >> 7, c = idx & 127;
    fb[idx] = f2b(c < 98 ? fnode[(size_t)n * 98 + c] : 0.0f);
}

// ---------------------------------------------------------------------------
// Template: BM=128, BN=64, BK=64. 256 threads = 4 waves (2M x 2N),
// wave tile 64x32, acc[4][2]. LDS: As 16KB + Bs 8KB swizzled (byte ^= (r&7)<<4).
DEV void ldA(const u16* __restrict__ g, size_t row0, int ld, int k0, int tid, uint4* v) {
    #pragma unroll
    for (int it = 0; it < 4; ++it) {
        int r = it * 32 + (tid >> 3);
        int c = (tid & 7) << 3;
        v[it] = *(const uint4*)(g + (row0 + (size_t)r) * ld + k0 + c);
    }
}
DEV void ldB(const u16* __restrict__ g, size_t row0, int ld, int k0, int tid, uint4* v) {
    #pragma unroll
    for (int it = 0; it < 2; ++it) {
        int r = it * 32 + (tid >> 3);
        int c = (tid & 7) << 3;
        v[it] = *(const uint4*)(g + (row0 + (size_t)r) * ld + k0 + c);
    }
}
DEV void wrA(u16* s, int tid, const uint4* v) {
    #pragma unroll
    for (int it = 0; it < 4; ++it) {
        int r = it * 32 + (tid >> 3);
        int c = (tid & 7) << 3;
        int byte = (((r << 6) + c) << 1) ^ ((r & 7) << 4);
        *(uint4*)((char*)s + byte) = v[it];
    }
}
DEV void wrB(u16* s, int tid, const uint4* v) {
    #pragma unroll
    for (int it = 0; it < 2; ++it) {
        int r = it * 32 + (tid >> 3);
        int c = (tid & 7) << 3;
        int byte = (((r << 6) + c) << 1) ^ ((r & 7) << 4);
        *(uint4*)((char*)s + byte) = v[it];
    }
}
// Swapped-operand MFMA: acc[i][j][q] = C[row_l+16i][col_l+16j+q]
DEV void mma_step(const u16* As, const u16* Bs, f32x4 acc[4][2], int lane, int wr, int wc) {
    int rb = (wr << 6) + (lane & 15);
    int cb = (wc << 5) + (lane & 15);
    int ko = (lane >> 4) << 3;
    #pragma unroll
    for (int kh = 0; kh < 2; ++kh) {
        bf16x8 a[4], b[2];
        #pragma unroll
        for (int i = 0; i < 4; ++i) {
            int ar = rb + (i << 4);
            a[i] = *(const bf16x8*)((const char*)As +
                   ((((ar << 6) + (kh << 5) + ko) << 1) ^ ((ar & 7) << 4)));
        }
        #pragma unroll
        for (int j = 0; j < 2; ++j) {
            int br = cb + (j << 4);
            b[j] = *(const bf16x8*)((const char*)Bs +
                   ((((br << 6) + (kh << 5) + ko) << 1) ^ ((br & 7) << 4)));
        }
        #pragma unroll
        for (int i = 0; i < 4; ++i)
            #pragma unroll
            for (int j = 0; j < 2; ++j)
                acc[i][j] = __builtin_amdgcn_mfma_f32_16x16x32_bf16(b[j], a[i], acc[i][j], 0, 0, 0);
    }
}

#define GT_PROLOG()                                            \
    __shared__ u16 As[8192], Bs[4096];                         \
    int tid = threadIdx.x, lane = tid & 63, w = tid >> 6;      \
    int wr = w >> 1, wc = w & 1;                               \
    int bm = blockIdx.x >> 2, bn = blockIdx.x & 3;             \
    size_t m0 = (size_t)bm << 7; size_t n0 = (size_t)(bn << 6);\
    int row_l = (wr << 6) + (lane & 15);                       \
    int col_l = (wc << 5) + ((lane >> 4) << 2);                \
    uint4 ra[4], rb_[2];

#define ACC_INIT(A)                                            \
    { f32x4 zz = {0.f, 0.f, 0.f, 0.f};                         \
      _Pragma("unroll") for (int i = 0; i < 4; ++i)            \
      _Pragma("unroll") for (int j = 0; j < 2; ++j) A[i][j] = zz; }

// Straight-line pipelined step: write staged regs to LDS, barrier, issue next
// loads (statically known), mma into a statically-chosen acc, barrier.
#define STEP_MID(LD_NEXT, ACC)                                 \
    wrA(As, tid, ra); wrB(Bs, tid, rb_);                       \
    __syncthreads();                                           \
    LD_NEXT;                                                   \
    mma_step(As, Bs, ACC, lane, wr, wc);                       \
    __syncthreads();
#define STEP_LAST(ACC)                                         \
    wrA(As, tid, ra); wrB(Bs, tid, rb_);                       \
    __syncthreads();                                           \
    mma_step(As, Bs, ACC, lane, wr, wc);
#define LD2(AG, ALD, AK, BG, BK)                               \
    (ldA(AG, m0, ALD, AK, tid, ra), ldB(BG, n0, (AG==x||AG==fb)?0:0, 0, tid, rb_))

// ---------------------------------------------------------------------------
// Fused GRU step: z=sigm([x|sumh]@Bz+bz); pre=tanh([x|sumgh]@Bh+bh);
// h=((1-z)*sumh+z*pre)*emask. 12 static segments. Grid 1252.
__global__ __launch_bounds__(256) void k_mg_fused(
    const u16* __restrict__ x, const u16* __restrict__ sumh,
    const u16* __restrict__ sumgh, const u16* __restrict__ BzT,
    const u16* __restrict__ BhT, const float* __restrict__ bz,
    const float* __restrict__ bh, u16* __restrict__ h) {
    GT_PROLOG()
    f32x4 aZ[4][2], aH[4][2]; ACC_INIT(aZ) ACC_INIT(aH)
    ldA(x, m0, 128, 0, tid, ra); ldB(BzT, n0, 384, 0, tid, rb_);
    // ---- Z phase: x(0,64)·Bz(0,64) + sumh(0..192)·Bz(128..320)
    STEP_MID((ldA(x, m0, 128, 64, tid, ra),      ldB(BzT, n0, 384, 64,  tid, rb_)), aZ)
    STEP_MID((ldA(sumh, m0, 256, 0, tid, ra),    ldB(BzT, n0, 384, 128, tid, rb_)), aZ)
    STEP_MID((ldA(sumh, m0, 256, 64, tid, ra),   ldB(BzT, n0, 384, 192, tid, rb_)), aZ)
    STEP_MID((ldA(sumh, m0, 256, 128, tid, ra),  ldB(BzT, n0, 384, 256, tid, rb_)), aZ)
    STEP_MID((ldA(sumh, m0, 256, 192, tid, ra),  ldB(BzT, n0, 384, 320, tid, rb_)), aZ)
    STEP_MID((ldA(x, m0, 128, 0, tid, ra),       ldB(BhT, n0, 384, 0,   tid, rb_)), aZ)
    // ---- H phase: x(0,64)·Bh(0,64) + sumgh(0..192)·Bh(128..320)
    STEP_MID((ldA(x, m0, 128, 64, tid, ra),      ldB(BhT, n0, 384, 64,  tid, rb_)), aH)
    STEP_MID((ldA(sumgh, m0, 256, 0, tid, ra),   ldB(BhT, n0, 384, 128, tid, rb_)), aH)
    STEP_MID((ldA(sumgh, m0, 256, 64, tid, ra),  ldB(BhT, n0, 384, 192, tid, rb_)), aH)
    STEP_MID((ldA(sumgh, m0, 256, 128, tid, ra), ldB(BhT, n0, 384, 256, tid, rb_)), aH)
    STEP_MID((ldA(sumgh, m0, 256, 192, tid, ra), ldB(BhT, n0, 384, 320, tid, rb_)), aH)
    STEP_LAST(aH)
    #pragma unroll
    for (int mi = 0; mi < 4; ++mi) {
        int m = (int)m0 + row_l + (mi << 4);
        if (m >= 40000) continue;
        #pragma unroll
        for (int ni = 0; ni < 2; ++ni) {
            int col = (int)n0 + col_l + (ni << 4);
            float4 vz = *(const float4*)(bz + col);
            float4 vh = *(const float4*)(bh + col);
            ushort4 sh4 = *(const ushort4*)(sumh + (size_t)m * 256 + col);
            float shv[4] = {b2f(sh4.x), b2f(sh4.y), b2f(sh4.z), b2f(sh4.w)};
            float bzv[4] = {vz.x, vz.y, vz.z, vz.w};
            float bhv[4] = {vh.x, vh.y, vh.z, vh.w};
            float o[4];
            #pragma unroll
            for (int q = 0; q < 4; ++q) {
                float z   = sigm(aZ[mi][ni][q] + bzv[q]);
                float pre = tanh_(aH[mi][ni][q] + bhv[q]);
                o[q] = (1.0f - z) * shv[q] + z * pre;
            }
            if (m == 0) { o[0] = o[1] = o[2] = o[3] = 0.0f; }
            ushort4 ov;
            ov.x = f2b(o[0]); ov.y = f2b(o[1]); ov.z = f2b(o[2]); ov.w = f2b(o[3]);
            *(ushort4*)(h + (size_t)m * 256 + col) = ov;
        }
    }
}

// Uh = h @ BuT^T. 4 static segments. Grid 1252.
__global__ __launch_bounds__(256) void k_mg_uh(
    const u16* __restrict__ A, const u16* __restrict__ BT, u16* __restrict__ C) {
    GT_PROLOG()
    f32x4 acc[4][2]; ACC_INIT(acc)
    ldA(A, m0, 256, 0, tid, ra); ldB(BT, n0, 256, 0, tid, rb_);
    STEP_MID((ldA(A, m0, 256, 64, tid, ra),  ldB(BT, n0, 256, 64,  tid, rb_)), acc)
    STEP_MID((ldA(A, m0, 256, 128, tid, ra), ldB(BT, n0, 256, 128, tid, rb_)), acc)
    STEP_MID((ldA(A, m0, 256, 192, tid, ra), ldB(BT, n0, 256, 192, tid, rb_)), acc)
    STEP_LAST(acc)
    #pragma unroll
    for (int mi = 0; mi < 4; ++mi) {
        int m = (int)m0 + row_l + (mi << 4);
        if (m >= 40000) continue;
        #pragma unroll
        for (int ni = 0; ni < 2; ++ni) {
            int col = (int)n0 + col_l + (ni << 4);
            ushort4 o;
            o.x = f2b(acc[mi][ni][0]); o.y = f2b(acc[mi][ni][1]);
            o.z = f2b(acc[mi][ni][2]); o.w = f2b(acc[mi][ni][3]);
            *(ushort4*)(C + (size_t)m * 256 + col) = o;
        }
    }
}

// PrU = x @ BrT^T + urb. 2 static segments. Grid 1252.
__global__ __launch_bounds__(256) void k_mg_p(
    const u16* __restrict__ x, const u16* __restrict__ BrT,
    const float* __restrict__ urb, u16* __restrict__ PrU) {
    GT_PROLOG()
    f32x4 acc[4][2]; ACC_INIT(acc)
    ldA(x, m0, 128, 0, tid, ra); ldB(BrT, n0, 128, 0, tid, rb_);
    STEP_MID((ldA(x, m0, 128, 64, tid, ra), ldB(BrT, n0, 128, 64, tid, rb_)), acc)
    STEP_LAST(acc)
    #pragma unroll
    for (int mi = 0; mi < 4; ++mi) {
        int m = (int)m0 + row_l + (mi << 4);
        if (m >= 40000) continue;
        #pragma unroll
        for (int ni = 0; ni < 2; ++ni) {
            int col = (int)n0 + col_l + (ni << 4);
            float4 ub = *(const float4*)(urb + col);
            ushort4 o;
            o.x = f2b(acc[mi][ni][0] + ub.x); o.y = f2b(acc[mi][ni][1] + ub.y);
            o.z = f2b(acc[mi][ni][2] + ub.z); o.w = f2b(acc[mi][ni][3] + ub.w);
            *(ushort4*)(PrU + (size_t)m * 256 + col) = o;
        }
    }
}

// Depth-1: h = sigm(x@Bzx+bz)*tanh(x@Bhx+bh). 4 static segments. Grid 1252.
__global__ __launch_bounds__(256) void k_d1(
    const u16* __restrict__ x, const u16* __restrict__ BzT,
    const u16* __restrict__ BhT, const float* __restrict__ bz,
    const float* __restrict__ bh, u16* __restrict__ h) {
    GT_PROLOG()
    f32x4 aZ[4][2], aH[4][2]; ACC_INIT(aZ) ACC_INIT(aH)
    ldA(x, m0, 128, 0, tid, ra); ldB(BzT, n0, 384, 0, tid, rb_);
    STEP_MID((ldA(x, m0, 128, 64, tid, ra), ldB(BzT, n0, 384, 64, tid, rb_)), aZ)
    STEP_MID((ldA(x, m0, 128, 0, tid, ra),  ldB(BhT, n0, 384, 0,  tid, rb_)), aZ)
    STEP_MID((ldA(x, m0, 128, 64, tid, ra), ldB(BhT, n0, 384, 64, tid, rb_)), aH)
    STEP_LAST(aH)
    #pragma unroll
    for (int mi = 0; mi < 4; ++mi) {
        int m = (int)m0 + row_l + (mi << 4);
        if (m >= 40000) continue;
        #pragma unroll
        for (int ni = 0; ni < 2; ++ni) {
            int col = (int)n0 + col_l + (ni << 4);
            float4 vz = *(const float4*)(bz + col);
            float4 vh = *(const float4*)(bh + col);
            float r[4];
            r[0] = sigm(aZ[mi][ni][0] + vz.x) * tanh_(aH[mi][ni][0] + vh.x);
            r[1] = sigm(aZ[mi][ni][1] + vz.y) * tanh_(aH[mi][ni][1] + vh.y);
            r[2] = sigm(aZ[mi][ni][2] + vz.z) * tanh_(aH[mi][ni][2] + vh.z);
            r[3] = sigm(aZ[mi][ni][3] + vz.w) * tanh_(aH[mi][ni][3] + vh.w);
            if (m == 0) { r[0] = r[1] = r[2] = r[3] = 0.0f; }
            ushort4 o;
            o.x = f2b(r[0]); o.y = f2b(r[1]); o.z = f2b(r[2]); o.w = f2b(r[3]);
            *(ushort4*)(h + (size_t)m * 256 + col) = o;
        }
    }
}

// out = gelu([fb|nei]@Bo + bo). 6 static segments. Grid 628. f32 out, row0 masked.
__global__ __launch_bounds__(256) void k_mg_out(
    const u16* __restrict__ fb, const u16* __restrict__ nei,
    const u16* __restrict__ BoT, const float* __restrict__ bo,
    float* __restrict__ out) {
    GT_PROLOG()
    f32x4 acc[4][2]; ACC_INIT(acc)
    ldA(fb, m0, 128, 0, tid, ra); ldB(BoT, n0, 384, 0, tid, rb_);
    STEP_MID((ldA(fb, m0, 128, 64, tid, ra),   ldB(BoT, n0, 384, 64,  tid, rb_)), acc)
    STEP_MID((ldA(nei, m0, 256, 0, tid, ra),   ldB(BoT, n0, 384, 128, tid, rb_)), acc)
    STEP_MID((ldA(nei, m0, 256, 64, tid, ra),  ldB(BoT, n0, 384, 192, tid, rb_)), acc)
    STEP_MID((ldA(nei, m0, 256, 128, tid, ra), ldB(BoT, n0, 384, 256, tid, rb_)), acc)
    STEP_MID((ldA(nei, m0, 256, 192, tid, ra), ldB(BoT, n0, 384, 320, tid, rb_)), acc)
    STEP_LAST(acc)
    #pragma unroll
    for (int mi = 0; mi < 4; ++mi) {
        int m = (int)m0 + row_l + (mi << 4);
        if (m >= 20000) continue;
        #pragma unroll
        for (int ni = 0; ni < 2; ++ni) {
            int col = (int)n0 + col_l + (ni << 4);
            float4 vb = *(const float4*)(bo + col);
            float4 o;
            o.x = gelu_(acc[mi][ni][0] + vb.x);
            o.y = gelu_(acc[mi][ni][1] + vb.y);
            o.z = gelu_(acc[mi][ni][2] + vb.z);
            o.w = gelu_(acc[mi][ni][3] + vb.w);
            if (m == 0) { o.x = o.y = o.z = o.w = 0.0f; }
            *(float4*)(out + (size_t)m * 256 + col) = o;
        }
    }
}

// ---------------------------------------------------------------------------
// sumh/sumgh gather. Grid 5000x256.
__global__ __launch_bounds__(256) void k_gather_edge(
    const u16* __restrict__ h, const u16* __restrict__ Uh,
    const u16* __restrict__ PrU, const int* __restrict__ bgraph,
    u16* __restrict__ sumh, u16* __restrict__ sumgh) {
    int e = (blockIdx.x << 3) + (threadIdx.x >> 5);
    int c = (threadIdx.x & 31) << 3;
    size_t o = (size_t)e * 256 + c;
    float pr[8];
    u4tof8(*(const uint4*)(PrU + o), pr);
    float sh[8] = {}, sg[8] = {};
    #pragma unroll
    for (int j = 0; j < 6; ++j) {
        int b = bgraph[e * 6 + j];
        float hv[8], uv[8];
        u4tof8(*(const uint4*)(h  + (size_t)b * 256 + c), hv);
        u4tof8(*(const uint4*)(Uh + (size_t)b * 256 + c), uv);
        #pragma unroll
        for (int q = 0; q < 8; ++q) {
            sh[q] += hv[q];
            sg[q] += sigm(pr[q] + uv[q]) * hv[q];
        }
    }
    *(uint4*)(sumh  + o) = f8tou4(sh);
    *(uint4*)(sumgh + o) = f8tou4(sg);
}

// nei[n] = bf16(sum_j h[agraph[n][j]]). Grid 2500x256.
__global__ __launch_bounds__(256) void k_gather_node(
    const u16* __restrict__ h, const int* __restrict__ agraph,
    u16* __restrict__ nei) {
    int n = (blockIdx.x << 3) + (threadIdx.x >> 5);
    int c = (threadIdx.x & 31) << 3;
    float s[8] = {};
    #pragma unroll
    for (int j = 0; j < 6; ++j) {
        int a = agraph[n * 6 + j];
        float hv[8];
        u4tof8(*(const uint4*)(h + (size_t)a * 256 + c), hv);
        #pragma unroll
        for (int q = 0; q < 8; ++q) s[q] += hv[q];
    }
    *(uint4*)(nei + (size_t)n * 256 + c) = f8tou4(s);
}

// ---------------------------------------------------------------------------
extern "C" void kernel_launch(void* const* d_in, const int* in_sizes, int n_in,
                              void* d_out, int out_size, void* d_ws, size_t ws_size,
                              hipStream_t stream) {
    if (ws_size < WS_BYTES) return;

    const float* fnode  = (const float*)d_in[0];
    const float* fmess  = (const float*)d_in[1];
    const int*   agraph = (const int*)d_in[2];
    const int*   bgraph = (const int*)d_in[3];
    const float* Wz  = (const float*)d_in[4];
    const float* bz  = (const float*)d_in[5];
    const float* Wr  = (const float*)d_in[6];
    const float* Ur  = (const float*)d_in[7];
    const float* urb = (const float*)d_in[8];
    const float* Wh  = (const float*)d_in[9];
    const float* bh  = (const float*)d_in[10];
    const float* Wo  = (const float*)d_in[11];
    const float* bo  = (const float*)d_in[12];

    char* base = (char*)d_ws;
    u16* x     = (u16*)(base + OB_X);
    u16* fb    = (u16*)(base + OB_FB);
    u16* PrU   = (u16*)(base + OB_PRU);
    u16* h     = (u16*)(base + OB_H);
    u16* Uh    = (u16*)(base + OB_UH);
    u16* nei   = (u16*)(base + OB_UH);   // overlay after depth loop
    u16* sumh  = (u16*)(base + OB_SH);
    u16* sumgh = (u16*)(base + OB_SGH);
    u16* BzT   = (u16*)(base + OB_BZ);
    u16* BhT   = (u16*)(base + OB_BH);
    u16* BuT   = (u16*)(base + OB_BU);
    u16* BrT   = (u16*)(base + OB_BR);
    u16* BoT   = (u16*)(base + OB_BO);
    float* out = (float*)d_out;

    hipLaunchKernelGGL(k_repack, dim3(384), dim3(256), 0, stream,
                       Wz, Wr, Ur, Wh, Wo, BzT, BhT, BuT, BrT, BoT);
    hipLaunchKernelGGL(k_build_x, dim3(20000), dim3(256), 0, stream, fnode, fmess, x);
    hipLaunchKernelGGL(k_build_fb, dim3(10000), dim3(256), 0, stream, fnode, fb);
    hipLaunchKernelGGL(k_mg_p, dim3(1252), dim3(256), 0, stream, x, BrT, urb, PrU);
    hipLaunchKernelGGL(k_d1,   dim3(1252), dim3(256), 0, stream, x, BzT, BhT, bz, bh, h);
    for (int d = 1; d < 4; ++d) {
        hipLaunchKernelGGL(k_mg_uh, dim3(1252), dim3(256), 0, stream, h, BuT, Uh);
        hipLaunchKernelGGL(k_gather_edge, dim3(5000), dim3(256), 0, stream,
                           h, Uh, PrU, bgraph, sumh, sumgh);
        hipLaunchKernelGGL(k_mg_fused, dim3(1252), dim3(256), 0, stream,
                           x, sumh, sumgh, BzT, BhT, bz, bh, h);
    }
    hipLaunchKernelGGL(k_gather_node, dim3(2500), dim3(256), 0, stream, h, agraph, nei);
    hipLaunchKernelGGL(k_mg_out, dim3(628), dim3(256), 0, stream, fb, nei, BoT, bo, out);
}

// Round 7
// 740.194 us; speedup vs baseline: 1.0551x; 1.0551x over previous
//
#include <hip/hip_runtime.h>
#include <cstddef>
#include <cstdint>

typedef unsigned short u16;
typedef unsigned int   u32;
typedef __bf16  bf16x8 __attribute__((ext_vector_type(8)));
typedef float   f32x4  __attribute__((ext_vector_type(4)));

#define DEV __device__ __forceinline__

DEV float b2f(u16 u) { union { u32 i; float f; } c; c.i = ((u32)u) << 16; return c.f; }
DEV u16 f2b(float x) { union { float f; u32 i; } c; c.f = x; u32 b = c.i;
                       return (u16)((b + 0x7FFFu + ((b >> 16) & 1u)) >> 16); }
DEV float sigm(float x)  { return 1.0f / (1.0f + __expf(-x)); }
DEV float tanh_(float x) { return 1.0f - 2.0f / (1.0f + __expf(2.0f * x)); }
DEV float gelu_(float x) { return 0.5f * x * (1.0f + erff(x * 0.70710678118654752f)); }

DEV void u4tof8(uint4 v, float* f) {
    f[0] = b2f((u16)(v.x & 0xFFFF)); f[1] = b2f((u16)(v.x >> 16));
    f[2] = b2f((u16)(v.y & 0xFFFF)); f[3] = b2f((u16)(v.y >> 16));
    f[4] = b2f((u16)(v.z & 0xFFFF)); f[5] = b2f((u16)(v.z >> 16));
    f[6] = b2f((u16)(v.w & 0xFFFF)); f[7] = b2f((u16)(v.w >> 16));
}
DEV uint4 f8tou4(const float* f) {
    uint4 v;
    v.x = (u32)f2b(f[0]) | ((u32)f2b(f[1]) << 16);
    v.y = (u32)f2b(f[2]) | ((u32)f2b(f[3]) << 16);
    v.z = (u32)f2b(f[4]) | ((u32)f2b(f[5]) << 16);
    v.w = (u32)f2b(f[6]) | ((u32)f2b(f[7]) << 16);
    return v;
}

// ---- workspace byte offsets; total 118,546,432 B (fits: 144,113,664 proven) ----
#define OB_X     0ull            // x  [40000][128] bf16
#define OB_FB    10240000ull     // fb [20000][128] bf16
#define OB_PRU   15360000ull     // PrU [40000][256] bf16 (= x@Wr^T + urb)
#define OB_H     35840000ull     // h   [40000][256] bf16
#define OB_UH    56320000ull     // Uh  [40000][256] bf16 ; nei overlays after loop
#define OB_SH    76800000ull     // sumh  [40000][256] bf16
#define OB_SGH   97280000ull     // sumgh [40000][256] bf16
#define OB_BZ    117760000ull    // BzT [256][384] bf16 : Wz[:, :111]|pad|Wz[:,111:]
#define OB_BH    117956608ull    // BhT [256][384] bf16
#define OB_BU    118153216ull    // BuT [256][256] bf16
#define OB_BR    118284288ull    // BrT [256][128] bf16 (Wr, K-pad)
#define OB_BO    118349824ull    // BoT [256][384] bf16 : Wo[:, :98]|pad|Wo[:,98:]
#define WS_BYTES 118546432ull

// ---------------------------------------------------------------------------
// Weight repack -> [N][K] bf16. Grid 384x256.
__global__ __launch_bounds__(256) void k_repack(
    const float* __restrict__ Wz, const float* __restrict__ Wr,
    const float* __restrict__ Ur, const float* __restrict__ Wh,
    const float* __restrict__ Wo,
    u16* __restrict__ BzT, u16* __restrict__ BhT, u16* __restrict__ BuT,
    u16* __restrict__ BrT, u16* __restrict__ BoT) {
    int idx = blockIdx.x * 256 + threadIdx.x;   // 0..98303
    {
        int n = idx / 384, k = idx % 384;
        float vz, vh, vo;
        if (k < 111)      { vz = Wz[n * 367 + k];      vh = Wh[n * 367 + k]; }
        else if (k < 128) { vz = 0.0f;                 vh = 0.0f; }
        else              { vz = Wz[n * 367 + k - 17]; vh = Wh[n * 367 + k - 17]; }
        if (k < 98)       vo = Wo[n * 354 + k];
        else if (k < 128) vo = 0.0f;
        else              vo = Wo[n * 354 + k - 30];
        BzT[idx] = f2b(vz); BhT[idx] = f2b(vh); BoT[idx] = f2b(vo);
    }
    if (idx < 65536) BuT[idx] = f2b(Ur[idx]);
    if (idx < 32768) {
        int n = idx >> 7, k = idx & 127;
        BrT[idx] = f2b(k < 111 ? Wr[n * 111 + k] : 0.0f);
    }
}

// x[e][c] (bf16, [40000][128], zero pad). Grid 20000x256 (2 edges/block).
__global__ __launch_bounds__(256) void k_build_x(const float* __restrict__ fnode,
                                                 const float* __restrict__ fmess,
                                                 u16* __restrict__ x) {
    int e = (blockIdx.x << 1) + (threadIdx.x >> 7);
    int c = threadIdx.x & 127;
    int src = (int)fmess[(size_t)e * 15];
    float v = 0.0f;
    if (c < 98)       v = fnode[(size_t)src * 98 + c];
    else if (c < 111) v = fmess[(size_t)e * 15 + 2 + (c - 98)];
    x[(size_t)e * 128 + c] = f2b(v);
}

// fb [20000][128] bf16 zero-padded. Grid 10000x256.
__global__ __launch_bounds__(256) void k_build_fb(const float* __restrict__ fnode,
                                                  u16* __restrict__ fb) {
    int idx = blockIdx.x * 256 + threadIdx.x;
    int n = idx >> 7, c = idx & 127;
    fb[idx] = f2b(c < 98 ? fnode[(size_t)n * 98 + c] : 0.0f);
}

// ---------------------------------------------------------------------------
// Template: BM=128, BN=64, BK=64. 256 threads = 4 waves (2M x 2N),
// wave tile 64x32, acc[4][2]. LDS: As 16KB + Bs 8KB swizzled (byte ^= (r&7)<<4).
// __launch_bounds__(256, 3): min 3 waves/EU -> VGPR cap ~168. Without it the
// LDS-derived occupancy heuristic (24KB -> 6 waves/EU) capped VGPRs at ~85 and
// spilled the 64-VGPR accumulators to scratch (R5/R6: 191MB WRITE_SIZE).
DEV void ldA(const u16* __restrict__ g, size_t row0, int ld, int k0, int tid, uint4* v) {
    #pragma unroll
    for (int it = 0; it < 4; ++it) {
        int r = it * 32 + (tid >> 3);
        int c = (tid & 7) << 3;
        v[it] = *(const uint4*)(g + (row0 + (size_t)r) * ld + k0 + c);
    }
}
DEV void ldB(const u16* __restrict__ g, size_t row0, int ld, int k0, int tid, uint4* v) {
    #pragma unroll
    for (int it = 0; it < 2; ++it) {
        int r = it * 32 + (tid >> 3);
        int c = (tid & 7) << 3;
        v[it] = *(const uint4*)(g + (row0 + (size_t)r) * ld + k0 + c);
    }
}
DEV void wrA(u16* s, int tid, const uint4* v) {
    #pragma unroll
    for (int it = 0; it < 4; ++it) {
        int r = it * 32 + (tid >> 3);
        int c = (tid & 7) << 3;
        int byte = (((r << 6) + c) << 1) ^ ((r & 7) << 4);
        *(uint4*)((char*)s + byte) = v[it];
    }
}
DEV void wrB(u16* s, int tid, const uint4* v) {
    #pragma unroll
    for (int it = 0; it < 2; ++it) {
        int r = it * 32 + (tid >> 3);
        int c = (tid & 7) << 3;
        int byte = (((r << 6) + c) << 1) ^ ((r & 7) << 4);
        *(uint4*)((char*)s + byte) = v[it];
    }
}
// Swapped-operand MFMA: acc[i][j][q] = C[row_l+16i][col_l+16j+q]
DEV void mma_step(const u16* As, const u16* Bs, f32x4 acc[4][2], int lane, int wr, int wc) {
    int rb = (wr << 6) + (lane & 15);
    int cb = (wc << 5) + (lane & 15);
    int ko = (lane >> 4) << 3;
    #pragma unroll
    for (int kh = 0; kh < 2; ++kh) {
        bf16x8 a[4], b[2];
        #pragma unroll
        for (int i = 0; i < 4; ++i) {
            int ar = rb + (i << 4);
            a[i] = *(const bf16x8*)((const char*)As +
                   ((((ar << 6) + (kh << 5) + ko) << 1) ^ ((ar & 7) << 4)));
        }
        #pragma unroll
        for (int j = 0; j < 2; ++j) {
            int br = cb + (j << 4);
            b[j] = *(const bf16x8*)((const char*)Bs +
                   ((((br << 6) + (kh << 5) + ko) << 1) ^ ((br & 7) << 4)));
        }
        #pragma unroll
        for (int i = 0; i < 4; ++i)
            #pragma unroll
            for (int j = 0; j < 2; ++j)
                acc[i][j] = __builtin_amdgcn_mfma_f32_16x16x32_bf16(b[j], a[i], acc[i][j], 0, 0, 0);
    }
}

#define GT_PROLOG()                                            \
    __shared__ u16 As[8192], Bs[4096];                         \
    int tid = threadIdx.x, lane = tid & 63, w = tid >> 6;      \
    int wr = w >> 1, wc = w & 1;                               \
    int bm = blockIdx.x >> 2, bn = blockIdx.x & 3;             \
    size_t m0 = (size_t)bm << 7; size_t n0 = (size_t)(bn << 6);\
    int row_l = (wr << 6) + (lane & 15);                       \
    int col_l = (wc << 5) + ((lane >> 4) << 2);                \
    uint4 ra[4], rb_[2];

#define ACC_INIT(A)                                            \
    { f32x4 zz = {0.f, 0.f, 0.f, 0.f};                         \
      _Pragma("unroll") for (int i = 0; i < 4; ++i)            \
      _Pragma("unroll") for (int j = 0; j < 2; ++j) A[i][j] = zz; }

// Straight-line pipelined step: write staged regs to LDS, barrier, issue next
// loads (statically known), mma into a statically-chosen acc, barrier.
#define STEP_MID(LD_NEXT, ACC)                                 \
    wrA(As, tid, ra); wrB(Bs, tid, rb_);                       \
    __syncthreads();                                           \
    LD_NEXT;                                                   \
    mma_step(As, Bs, ACC, lane, wr, wc);                       \
    __syncthreads();
#define STEP_LAST(ACC)                                         \
    wrA(As, tid, ra); wrB(Bs, tid, rb_);                       \
    __syncthreads();                                           \
    mma_step(As, Bs, ACC, lane, wr, wc);

// ---------------------------------------------------------------------------
// Fused GRU step: z=sigm([x|sumh]@Bz+bz); pre=tanh([x|sumgh]@Bh+bh);
// h=((1-z)*sumh+z*pre)*emask. 12 static segments. Grid 1252.
__global__ __launch_bounds__(256, 3) void k_mg_fused(
    const u16* __restrict__ x, const u16* __restrict__ sumh,
    const u16* __restrict__ sumgh, const u16* __restrict__ BzT,
    const u16* __restrict__ BhT, const float* __restrict__ bz,
    const float* __restrict__ bh, u16* __restrict__ h) {
    GT_PROLOG()
    f32x4 aZ[4][2], aH[4][2]; ACC_INIT(aZ) ACC_INIT(aH)
    ldA(x, m0, 128, 0, tid, ra); ldB(BzT, n0, 384, 0, tid, rb_);
    // ---- Z phase: x(0,64)·Bz(0,64) + sumh(0..192)·Bz(128..320)
    STEP_MID((ldA(x, m0, 128, 64, tid, ra),      ldB(BzT, n0, 384, 64,  tid, rb_)), aZ)
    STEP_MID((ldA(sumh, m0, 256, 0, tid, ra),    ldB(BzT, n0, 384, 128, tid, rb_)), aZ)
    STEP_MID((ldA(sumh, m0, 256, 64, tid, ra),   ldB(BzT, n0, 384, 192, tid, rb_)), aZ)
    STEP_MID((ldA(sumh, m0, 256, 128, tid, ra),  ldB(BzT, n0, 384, 256, tid, rb_)), aZ)
    STEP_MID((ldA(sumh, m0, 256, 192, tid, ra),  ldB(BzT, n0, 384, 320, tid, rb_)), aZ)
    STEP_MID((ldA(x, m0, 128, 0, tid, ra),       ldB(BhT, n0, 384, 0,   tid, rb_)), aZ)
    // ---- H phase: x(0,64)·Bh(0,64) + sumgh(0..192)·Bh(128..320)
    STEP_MID((ldA(x, m0, 128, 64, tid, ra),      ldB(BhT, n0, 384, 64,  tid, rb_)), aH)
    STEP_MID((ldA(sumgh, m0, 256, 0, tid, ra),   ldB(BhT, n0, 384, 128, tid, rb_)), aH)
    STEP_MID((ldA(sumgh, m0, 256, 64, tid, ra),  ldB(BhT, n0, 384, 192, tid, rb_)), aH)
    STEP_MID((ldA(sumgh, m0, 256, 128, tid, ra), ldB(BhT, n0, 384, 256, tid, rb_)), aH)
    STEP_MID((ldA(sumgh, m0, 256, 192, tid, ra), ldB(BhT, n0, 384, 320, tid, rb_)), aH)
    STEP_LAST(aH)
    #pragma unroll
    for (int mi = 0; mi < 4; ++mi) {
        int m = (int)m0 + row_l + (mi << 4);
        if (m >= 40000) continue;
        #pragma unroll
        for (int ni = 0; ni < 2; ++ni) {
            int col = (int)n0 + col_l + (ni << 4);
            float4 vz = *(const float4*)(bz + col);
            float4 vh = *(const float4*)(bh + col);
            ushort4 sh4 = *(const ushort4*)(sumh + (size_t)m * 256 + col);
            float shv[4] = {b2f(sh4.x), b2f(sh4.y), b2f(sh4.z), b2f(sh4.w)};
            float bzv[4] = {vz.x, vz.y, vz.z, vz.w};
            float bhv[4] = {vh.x, vh.y, vh.z, vh.w};
            float o[4];
            #pragma unroll
            for (int q = 0; q < 4; ++q) {
                float z   = sigm(aZ[mi][ni][q] + bzv[q]);
                float pre = tanh_(aH[mi][ni][q] + bhv[q]);
                o[q] = (1.0f - z) * shv[q] + z * pre;
            }
            if (m == 0) { o[0] = o[1] = o[2] = o[3] = 0.0f; }
            ushort4 ov;
            ov.x = f2b(o[0]); ov.y = f2b(o[1]); ov.z = f2b(o[2]); ov.w = f2b(o[3]);
            *(ushort4*)(h + (size_t)m * 256 + col) = ov;
        }
    }
}

// Uh = h @ BuT^T. 4 static segments. Grid 1252.
__global__ __launch_bounds__(256, 3) void k_mg_uh(
    const u16* __restrict__ A, const u16* __restrict__ BT, u16* __restrict__ C) {
    GT_PROLOG()
    f32x4 acc[4][2]; ACC_INIT(acc)
    ldA(A, m0, 256, 0, tid, ra); ldB(BT, n0, 256, 0, tid, rb_);
    STEP_MID((ldA(A, m0, 256, 64, tid, ra),  ldB(BT, n0, 256, 64,  tid, rb_)), acc)
    STEP_MID((ldA(A, m0, 256, 128, tid, ra), ldB(BT, n0, 256, 128, tid, rb_)), acc)
    STEP_MID((ldA(A, m0, 256, 192, tid, ra), ldB(BT, n0, 256, 192, tid, rb_)), acc)
    STEP_LAST(acc)
    #pragma unroll
    for (int mi = 0; mi < 4; ++mi) {
        int m = (int)m0 + row_l + (mi << 4);
        if (m >= 40000) continue;
        #pragma unroll
        for (int ni = 0; ni < 2; ++ni) {
            int col = (int)n0 + col_l + (ni << 4);
            ushort4 o;
            o.x = f2b(acc[mi][ni][0]); o.y = f2b(acc[mi][ni][1]);
            o.z = f2b(acc[mi][ni][2]); o.w = f2b(acc[mi][ni][3]);
            *(ushort4*)(C + (size_t)m * 256 + col) = o;
        }
    }
}

// PrU = x @ BrT^T + urb. 2 static segments. Grid 1252.
__global__ __launch_bounds__(256, 3) void k_mg_p(
    const u16* __restrict__ x, const u16* __restrict__ BrT,
    const float* __restrict__ urb, u16* __restrict__ PrU) {
    GT_PROLOG()
    f32x4 acc[4][2]; ACC_INIT(acc)
    ldA(x, m0, 128, 0, tid, ra); ldB(BrT, n0, 128, 0, tid, rb_);
    STEP_MID((ldA(x, m0, 128, 64, tid, ra), ldB(BrT, n0, 128, 64, tid, rb_)), acc)
    STEP_LAST(acc)
    #pragma unroll
    for (int mi = 0; mi < 4; ++mi) {
        int m = (int)m0 + row_l + (mi << 4);
        if (m >= 40000) continue;
        #pragma unroll
        for (int ni = 0; ni < 2; ++ni) {
            int col = (int)n0 + col_l + (ni << 4);
            float4 ub = *(const float4*)(urb + col);
            ushort4 o;
            o.x = f2b(acc[mi][ni][0] + ub.x); o.y = f2b(acc[mi][ni][1] + ub.y);
            o.z = f2b(acc[mi][ni][2] + ub.z); o.w = f2b(acc[mi][ni][3] + ub.w);
            *(ushort4*)(PrU + (size_t)m * 256 + col) = o;
        }
    }
}

// Depth-1: h = sigm(x@Bzx+bz)*tanh(x@Bhx+bh). 4 static segments. Grid 1252.
__global__ __launch_bounds__(256, 3) void k_d1(
    const u16* __restrict__ x, const u16* __restrict__ BzT,
    const u16* __restrict__ BhT, const float* __restrict__ bz,
    const float* __restrict__ bh, u16* __restrict__ h) {
    GT_PROLOG()
    f32x4 aZ[4][2], aH[4][2]; ACC_INIT(aZ) ACC_INIT(aH)
    ldA(x, m0, 128, 0, tid, ra); ldB(BzT, n0, 384, 0, tid, rb_);
    STEP_MID((ldA(x, m0, 128, 64, tid, ra), ldB(BzT, n0, 384, 64, tid, rb_)), aZ)
    STEP_MID((ldA(x, m0, 128, 0, tid, ra),  ldB(BhT, n0, 384, 0,  tid, rb_)), aZ)
    STEP_MID((ldA(x, m0, 128, 64, tid, ra), ldB(BhT, n0, 384, 64, tid, rb_)), aH)
    STEP_LAST(aH)
    #pragma unroll
    for (int mi = 0; mi < 4; ++mi) {
        int m = (int)m0 + row_l + (mi << 4);
        if (m >= 40000) continue;
        #pragma unroll
        for (int ni = 0; ni < 2; ++ni) {
            int col = (int)n0 + col_l + (ni << 4);
            float4 vz = *(const float4*)(bz + col);
            float4 vh = *(const float4*)(bh + col);
            float r[4];
            r[0] = sigm(aZ[mi][ni][0] + vz.x) * tanh_(aH[mi][ni][0] + vh.x);
            r[1] = sigm(aZ[mi][ni][1] + vz.y) * tanh_(aH[mi][ni][1] + vh.y);
            r[2] = sigm(aZ[mi][ni][2] + vz.z) * tanh_(aH[mi][ni][2] + vh.z);
            r[3] = sigm(aZ[mi][ni][3] + vz.w) * tanh_(aH[mi][ni][3] + vh.w);
            if (m == 0) { r[0] = r[1] = r[2] = r[3] = 0.0f; }
            ushort4 o;
            o.x = f2b(r[0]); o.y = f2b(r[1]); o.z = f2b(r[2]); o.w = f2b(r[3]);
            *(ushort4*)(h + (size_t)m * 256 + col) = o;
        }
    }
}

// out = gelu([fb|nei]@Bo + bo). 6 static segments. Grid 628. f32 out, row0 masked.
__global__ __launch_bounds__(256, 3) void k_mg_out(
    const u16* __restrict__ fb, const u16* __restrict__ nei,
    const u16* __restrict__ BoT, const float* __restrict__ bo,
    float* __restrict__ out) {
    GT_PROLOG()
    f32x4 acc[4][2]; ACC_INIT(acc)
    ldA(fb, m0, 128, 0, tid, ra); ldB(BoT, n0, 384, 0, tid, rb_);
    STEP_MID((ldA(fb, m0, 128, 64, tid, ra),   ldB(BoT, n0, 384, 64,  tid, rb_)), acc)
    STEP_MID((ldA(nei, m0, 256, 0, tid, ra),   ldB(BoT, n0, 384, 128, tid, rb_)), acc)
    STEP_MID((ldA(nei, m0, 256, 64, tid, ra),  ldB(BoT, n0, 384, 192, tid, rb_)), acc)
    STEP_MID((ldA(nei, m0, 256, 128, tid, ra), ldB(BoT, n0, 384, 256, tid, rb_)), acc)
    STEP_MID((ldA(nei, m0, 256, 192, tid, ra), ldB(BoT, n0, 384, 320, tid, rb_)), acc)
    STEP_LAST(acc)
    #pragma unroll
    for (int mi = 0; mi < 4; ++mi) {
        int m = (int)m0 + row_l + (mi << 4);
        if (m >= 20000) continue;
        #pragma unroll
        for (int ni = 0; ni < 2; ++ni) {
            int col = (int)n0 + col_l + (ni << 4);
            float4 vb = *(const float4*)(bo + col);
            float4 o;
            o.x = gelu_(acc[mi][ni][0] + vb.x);
            o.y = gelu_(acc[mi][ni][1] + vb.y);
            o.z = gelu_(acc[mi][ni][2] + vb.z);
            o.w = gelu_(acc[mi][ni][3] + vb.w);
            if (m == 0) { o.x = o.y = o.z = o.w = 0.0f; }
            *(float4*)(out + (size_t)m * 256 + col) = o;
        }
    }
}

// ---------------------------------------------------------------------------
// sumh/sumgh gather. Grid 5000x256.
__global__ __launch_bounds__(256) void k_gather_edge(
    const u16* __restrict__ h, const u16* __restrict__ Uh,
    const u16* __restrict__ PrU, const int* __restrict__ bgraph,
    u16* __restrict__ sumh, u16* __restrict__ sumgh) {
    int e = (blockIdx.x << 3) + (threadIdx.x >> 5);
    int c = (threadIdx.x & 31) << 3;
    size_t o = (size_t)e * 256 + c;
    float pr[8];
    u4tof8(*(const uint4*)(PrU + o), pr);
    float sh[8] = {}, sg[8] = {};
    #pragma unroll
    for (int j = 0; j < 6; ++j) {
        int b = bgraph[e * 6 + j];
        float hv[8], uv[8];
        u4tof8(*(const uint4*)(h  + (size_t)b * 256 + c), hv);
        u4tof8(*(const uint4*)(Uh + (size_t)b * 256 + c), uv);
        #pragma unroll
        for (int q = 0; q < 8; ++q) {
            sh[q] += hv[q];
            sg[q] += sigm(pr[q] + uv[q]) * hv[q];
        }
    }
    *(uint4*)(sumh  + o) = f8tou4(sh);
    *(uint4*)(sumgh + o) = f8tou4(sg);
}

// nei[n] = bf16(sum_j h[agraph[n][j]]). Grid 2500x256.
__global__ __launch_bounds__(256) void k_gather_node(
    const u16* __restrict__ h, const int* __restrict__ agraph,
    u16* __restrict__ nei) {
    int n = (blockIdx.x << 3) + (threadIdx.x >> 5);
    int c = (threadIdx.x & 31) << 3;
    float s[8] = {};
    #pragma unroll
    for (int j = 0; j < 6; ++j) {
        int a = agraph[n * 6 + j];
        float hv[8];
        u4tof8(*(const uint4*)(h + (size_t)a * 256 + c), hv);
        #pragma unroll
        for (int q = 0; q < 8; ++q) s[q] += hv[q];
    }
    *(uint4*)(nei + (size_t)n * 256 + c) = f8tou4(s);
}

// ---------------------------------------------------------------------------
extern "C" void kernel_launch(void* const* d_in, const int* in_sizes, int n_in,
                              void* d_out, int out_size, void* d_ws, size_t ws_size,
                              hipStream_t stream) {
    if (ws_size < WS_BYTES) return;

    const float* fnode  = (const float*)d_in[0];
    const float* fmess  = (const float*)d_in[1];
    const int*   agraph = (const int*)d_in[2];
    const int*   bgraph = (const int*)d_in[3];
    const float* Wz  = (const float*)d_in[4];
    const float* bz  = (const float*)d_in[5];
    const float* Wr  = (const float*)d_in[6];
    const float* Ur  = (const float*)d_in[7];
    const float* urb = (const float*)d_in[8];
    const float* Wh  = (const float*)d_in[9];
    const float* bh  = (const float*)d_in[10];
    const float* Wo  = (const float*)d_in[11];
    const float* bo  = (const float*)d_in[12];

    char* base = (char*)d_ws;
    u16* x     = (u16*)(base + OB_X);
    u16* fb    = (u16*)(base + OB_FB);
    u16* PrU   = (u16*)(base + OB_PRU);
    u16* h     = (u16*)(base + OB_H);
    u16* Uh    = (u16*)(base + OB_UH);
    u16* nei   = (u16*)(base + OB_UH);   // overlay after depth loop
    u16* sumh  = (u16*)(base + OB_SH);
    u16* sumgh = (u16*)(base + OB_SGH);
    u16* BzT   = (u16*)(base + OB_BZ);
    u16* BhT   = (u16*)(base + OB_BH);
    u16* BuT   = (u16*)(base + OB_BU);
    u16* BrT   = (u16*)(base + OB_BR);
    u16* BoT   = (u16*)(base + OB_BO);
    float* out = (float*)d_out;

    hipLaunchKernelGGL(k_repack, dim3(384), dim3(256), 0, stream,
                       Wz, Wr, Ur, Wh, Wo, BzT, BhT, BuT, BrT, BoT);
    hipLaunchKernelGGL(k_build_x, dim3(20000), dim3(256), 0, stream, fnode, fmess, x);
    hipLaunchKernelGGL(k_build_fb, dim3(10000), dim3(256), 0, stream, fnode, fb);
    hipLaunchKernelGGL(k_mg_p, dim3(1252), dim3(256), 0, stream, x, BrT, urb, PrU);
    hipLaunchKernelGGL(k_d1,   dim3(1252), dim3(256), 0, stream, x, BzT, BhT, bz, bh, h);
    for (int d = 1; d < 4; ++d) {
        hipLaunchKernelGGL(k_mg_uh, dim3(1252), dim3(256), 0, stream, h, BuT, Uh);
        hipLaunchKernelGGL(k_gather_edge, dim3(5000), dim3(256), 0, stream,
                           h, Uh, PrU, bgraph, sumh, sumgh);
        hipLaunchKernelGGL(k_mg_fused, dim3(1252), dim3(256), 0, stream,
                           x, sumh, sumgh, BzT, BhT, bz, bh, h);
    }
    hipLaunchKernelGGL(k_gather_node, dim3(2500), dim3(256), 0, stream, h, agraph, nei);
    hipLaunchKernelGGL(k_mg_out, dim3(628), dim3(256), 0, stream, fb, nei, BoT, bo, out);
}

// Round 8
// 678.096 us; speedup vs baseline: 1.1517x; 1.0916x over previous
//
#include <hip/hip_runtime.h>
#include <cstddef>
#include <cstdint>

typedef unsigned short u16;
typedef unsigned int   u32;
typedef __bf16  bf16x8 __attribute__((ext_vector_type(8)));
typedef float   f32x4  __attribute__((ext_vector_type(4)));

#define DEV __device__ __forceinline__

DEV float b2f(u16 u) { union { u32 i; float f; } c; c.i = ((u32)u) << 16; return c.f; }
DEV u16 f2b(float x) { union { float f; u32 i; } c; c.f = x; u32 b = c.i;
                       return (u16)((b + 0x7FFFu + ((b >> 16) & 1u)) >> 16); }
DEV float sigm(float x)  { return 1.0f / (1.0f + __expf(-x)); }
DEV float tanh_(float x) { return 1.0f - 2.0f / (1.0f + __expf(2.0f * x)); }
DEV float gelu_(float x) { return 0.5f * x * (1.0f + erff(x * 0.70710678118654752f)); }

DEV void u4tof8(uint4 v, float* f) {
    f[0] = b2f((u16)(v.x & 0xFFFF)); f[1] = b2f((u16)(v.x >> 16));
    f[2] = b2f((u16)(v.y & 0xFFFF)); f[3] = b2f((u16)(v.y >> 16));
    f[4] = b2f((u16)(v.z & 0xFFFF)); f[5] = b2f((u16)(v.z >> 16));
    f[6] = b2f((u16)(v.w & 0xFFFF)); f[7] = b2f((u16)(v.w >> 16));
}
DEV uint4 f8tou4(const float* f) {
    uint4 v;
    v.x = (u32)f2b(f[0]) | ((u32)f2b(f[1]) << 16);
    v.y = (u32)f2b(f[2]) | ((u32)f2b(f[3]) << 16);
    v.z = (u32)f2b(f[4]) | ((u32)f2b(f[5]) << 16);
    v.w = (u32)f2b(f[6]) | ((u32)f2b(f[7]) << 16);
    return v;
}

// ---- workspace byte offsets; total 118,546,432 B (fits: 144,113,664 proven) ----
#define OB_X     0ull            // x  [40000][128] bf16
#define OB_FB    10240000ull     // fb [20000][128] bf16
#define OB_PRU   15360000ull     // PrU [40000][256] bf16 (= x@Wr^T + urb)
#define OB_H     35840000ull     // h   [40000][256] bf16
#define OB_UH    56320000ull     // Uh  [40000][256] bf16 ; nei overlays after loop
#define OB_SH    76800000ull     // sumh  [40000][256] bf16
#define OB_SGH   97280000ull     // sumgh [40000][256] bf16
#define OB_BZ    117760000ull    // BzT [256][384] bf16 : Wz[:, :111]|pad|Wz[:,111:]
#define OB_BH    117956608ull    // BhT [256][384] bf16
#define OB_BU    118153216ull    // BuT [256][256] bf16
#define OB_BR    118284288ull    // BrT [256][128] bf16 (Wr, K-pad)
#define OB_BO    118349824ull    // BoT [256][384] bf16 : Wo[:, :98]|pad|Wo[:,98:]
#define WS_BYTES 118546432ull

// ---------------------------------------------------------------------------
// Weight repack -> [N][K] bf16. Grid 384x256.
__global__ __launch_bounds__(256) void k_repack(
    const float* __restrict__ Wz, const float* __restrict__ Wr,
    const float* __restrict__ Ur, const float* __restrict__ Wh,
    const float* __restrict__ Wo,
    u16* __restrict__ BzT, u16* __restrict__ BhT, u16* __restrict__ BuT,
    u16* __restrict__ BrT, u16* __restrict__ BoT) {
    int idx = blockIdx.x * 256 + threadIdx.x;   // 0..98303
    {
        int n = idx / 384, k = idx % 384;
        float vz, vh, vo;
        if (k < 111)      { vz = Wz[n * 367 + k];      vh = Wh[n * 367 + k]; }
        else if (k < 128) { vz = 0.0f;                 vh = 0.0f; }
        else              { vz = Wz[n * 367 + k - 17]; vh = Wh[n * 367 + k - 17]; }
        if (k < 98)       vo = Wo[n * 354 + k];
        else if (k < 128) vo = 0.0f;
        else              vo = Wo[n * 354 + k - 30];
        BzT[idx] = f2b(vz); BhT[idx] = f2b(vh); BoT[idx] = f2b(vo);
    }
    if (idx < 65536) BuT[idx] = f2b(Ur[idx]);
    if (idx < 32768) {
        int n = idx >> 7, k = idx & 127;
        BrT[idx] = f2b(k < 111 ? Wr[n * 111 + k] : 0.0f);
    }
}

// x[e][c] (bf16, [40000][128], zero pad). Grid 20000x256 (2 edges/block).
__global__ __launch_bounds__(256) void k_build_x(const float* __restrict__ fnode,
                                                 const float* __restrict__ fmess,
                                                 u16* __restrict__ x) {
    int e = (blockIdx.x << 1) + (threadIdx.x >> 7);
    int c = threadIdx.x & 127;
    int src = (int)fmess[(size_t)e * 15];
    float v = 0.0f;
    if (c < 98)       v = fnode[(size_t)src * 98 + c];
    else if (c < 111) v = fmess[(size_t)e * 15 + 2 + (c - 98)];
    x[(size_t)e * 128 + c] = f2b(v);
}

// fb [20000][128] bf16 zero-padded. Grid 10000x256.
__global__ __launch_bounds__(256) void k_build_fb(const float* __restrict__ fnode,
                                                  u16* __restrict__ fb) {
    int idx = blockIdx.x * 256 + threadIdx.x;
    int n = idx >> 7, c = idx & 127;
    fb[idx] = f2b(c < 98 ? fnode[(size_t)n * 98 + c] : 0.0f);
}

// ---------------------------------------------------------------------------
// Template: BM=128, BN=64, BK=64. 256 threads = 4 waves (2M x 2N),
// wave tile 64x32, acc[4][2]. LDS swizzle: byte ^= (row&7)<<4.
// ALL MFMA kernels use exactly 48KB LDS: the backend's VGPR budget follows the
// LDS-implied blocks/CU (64KB->cap256 ok; 24KB->cap85 SPILLED in R5-R7).
// 48KB -> 3 blocks/CU -> cap ~170 >= our ~150 demand, and 3 blocks resident.
DEV void ldA(const u16* __restrict__ g, size_t row0, int ld, int k0, int tid, uint4* v) {
    #pragma unroll
    for (int it = 0; it < 4; ++it) {
        int r = it * 32 + (tid >> 3);
        int c = (tid & 7) << 3;
        v[it] = *(const uint4*)(g + (row0 + (size_t)r) * ld + k0 + c);
    }
}
DEV void ldB(const u16* __restrict__ g, size_t row0, int ld, int k0, int tid, uint4* v) {
    #pragma unroll
    for (int it = 0; it < 2; ++it) {
        int r = it * 32 + (tid >> 3);
        int c = (tid & 7) << 3;
        v[it] = *(const uint4*)(g + (row0 + (size_t)r) * ld + k0 + c);
    }
}
DEV void wrA(u16* s, int tid, const uint4* v) {
    #pragma unroll
    for (int it = 0; it < 4; ++it) {
        int r = it * 32 + (tid >> 3);
        int c = (tid & 7) << 3;
        int byte = (((r << 6) + c) << 1) ^ ((r & 7) << 4);
        *(uint4*)((char*)s + byte) = v[it];
    }
}
DEV void wrB(u16* s, int tid, const uint4* v) {
    #pragma unroll
    for (int it = 0; it < 2; ++it) {
        int r = it * 32 + (tid >> 3);
        int c = (tid & 7) << 3;
        int byte = (((r << 6) + c) << 1) ^ ((r & 7) << 4);
        *(uint4*)((char*)s + byte) = v[it];
    }
}
// Swapped-operand MFMA: acc[i][j][q] = C[row_l+16i][col_l+16j+q]
DEV void mma_step(const u16* As, const u16* Bs, f32x4 acc[4][2], int lane, int wr, int wc) {
    int rb = (wr << 6) + (lane & 15);
    int cb = (wc << 5) + (lane & 15);
    int ko = (lane >> 4) << 3;
    #pragma unroll
    for (int kh = 0; kh < 2; ++kh) {
        bf16x8 a[4], b[2];
        #pragma unroll
        for (int i = 0; i < 4; ++i) {
            int ar = rb + (i << 4);
            a[i] = *(const bf16x8*)((const char*)As +
                   ((((ar << 6) + (kh << 5) + ko) << 1) ^ ((ar & 7) << 4)));
        }
        #pragma unroll
        for (int j = 0; j < 2; ++j) {
            int br = cb + (j << 4);
            b[j] = *(const bf16x8*)((const char*)Bs +
                   ((((br << 6) + (kh << 5) + ko) << 1) ^ ((br & 7) << 4)));
        }
        #pragma unroll
        for (int i = 0; i < 4; ++i)
            #pragma unroll
            for (int j = 0; j < 2; ++j)
                acc[i][j] = __builtin_amdgcn_mfma_f32_16x16x32_bf16(b[j], a[i], acc[i][j], 0, 0, 0);
    }
}

#define GT_PROLOG()                                            \
    int tid = threadIdx.x, lane = tid & 63, w = tid >> 6;      \
    int wr = w >> 1, wc = w & 1;                               \
    int bm = blockIdx.x >> 2, bn = blockIdx.x & 3;             \
    size_t m0 = (size_t)bm << 7; size_t n0 = (size_t)(bn << 6);\
    int row_l = (wr << 6) + (lane & 15);                       \
    int col_l = (wc << 5) + ((lane >> 4) << 2);

#define ACC_INIT(A)                                            \
    { f32x4 zz = {0.f, 0.f, 0.f, 0.f};                         \
      _Pragma("unroll") for (int i = 0; i < 4; ++i)            \
      _Pragma("unroll") for (int j = 0; j < 2; ++j) A[i][j] = zz; }

// ---------------------------------------------------------------------------
// Fused GRU step: z=sigm([x|sumh]@Bz+bz); pre=tanh([x|sumgh]@Bh+bh);
// h=((1-z)*sumh+z*pre)*emask. 6 static K=64 steps, dual acc. Grid 1252. 48KB.
__global__ __launch_bounds__(256) void k_mg_fused(
    const u16* __restrict__ x, const u16* __restrict__ sumh,
    const u16* __restrict__ sumgh, const u16* __restrict__ BzT,
    const u16* __restrict__ BhT, const float* __restrict__ bz,
    const float* __restrict__ bh, u16* __restrict__ h) {
    __shared__ u16 As1[8192], As2[8192], Bs1[4096], Bs2[4096];
    GT_PROLOG()
    f32x4 aZ[4][2], aH[4][2]; ACC_INIT(aZ) ACC_INIT(aH)
    uint4 ra1[4], ra2[4], rb1[2], rb2[2];
    // step 0: A=x[k0], B=Bz[k0]/Bh[k0]  (As2 unused in x phase)
    ldA(x, m0, 128, 0, tid, ra1); ldB(BzT, n0, 384, 0, tid, rb1); ldB(BhT, n0, 384, 0, tid, rb2);
    wrA(As1, tid, ra1); wrB(Bs1, tid, rb1); wrB(Bs2, tid, rb2);
    __syncthreads();
    ldA(x, m0, 128, 64, tid, ra1); ldB(BzT, n0, 384, 64, tid, rb1); ldB(BhT, n0, 384, 64, tid, rb2);
    mma_step(As1, Bs1, aZ, lane, wr, wc); mma_step(As1, Bs2, aH, lane, wr, wc);
    __syncthreads();
    // step 1: A=x[k64]
    wrA(As1, tid, ra1); wrB(Bs1, tid, rb1); wrB(Bs2, tid, rb2);
    __syncthreads();
    ldA(sumh, m0, 256, 0, tid, ra1); ldA(sumgh, m0, 256, 0, tid, ra2);
    ldB(BzT, n0, 384, 128, tid, rb1); ldB(BhT, n0, 384, 128, tid, rb2);
    mma_step(As1, Bs1, aZ, lane, wr, wc); mma_step(As1, Bs2, aH, lane, wr, wc);
    __syncthreads();
    // steps 2..5: A1=sumh[k], A2=sumgh[k], B=Bz/Bh[128+k]
    #define F_STEP(KS, LAST)                                                     \
    {                                                                            \
        wrA(As1, tid, ra1); wrA(As2, tid, ra2);                                  \
        wrB(Bs1, tid, rb1); wrB(Bs2, tid, rb2);                                  \
        __syncthreads();                                                         \
        if (!(LAST)) {                                                           \
            ldA(sumh, m0, 256, (KS) + 64, tid, ra1);                             \
            ldA(sumgh, m0, 256, (KS) + 64, tid, ra2);                            \
            ldB(BzT, n0, 384, (KS) + 192, tid, rb1);                             \
            ldB(BhT, n0, 384, (KS) + 192, tid, rb2);                             \
        }                                                                        \
        mma_step(As1, Bs1, aZ, lane, wr, wc);                                    \
        mma_step(As2, Bs2, aH, lane, wr, wc);                                    \
        if (!(LAST)) __syncthreads();                                            \
    }
    F_STEP(0, 0) F_STEP(64, 0) F_STEP(128, 0) F_STEP(192, 1)
    #undef F_STEP
    #pragma unroll
    for (int mi = 0; mi < 4; ++mi) {
        int m = (int)m0 + row_l + (mi << 4);
        if (m >= 40000) continue;
        #pragma unroll
        for (int ni = 0; ni < 2; ++ni) {
            int col = (int)n0 + col_l + (ni << 4);
            float4 vz = *(const float4*)(bz + col);
            float4 vh = *(const float4*)(bh + col);
            ushort4 sh4 = *(const ushort4*)(sumh + (size_t)m * 256 + col);
            float shv[4] = {b2f(sh4.x), b2f(sh4.y), b2f(sh4.z), b2f(sh4.w)};
            float bzv[4] = {vz.x, vz.y, vz.z, vz.w};
            float bhv[4] = {vh.x, vh.y, vh.z, vh.w};
            float o[4];
            #pragma unroll
            for (int q = 0; q < 4; ++q) {
                float z   = sigm(aZ[mi][ni][q] + bzv[q]);
                float pre = tanh_(aH[mi][ni][q] + bhv[q]);
                o[q] = (1.0f - z) * shv[q] + z * pre;
            }
            if (m == 0) { o[0] = o[1] = o[2] = o[3] = 0.0f; }
            ushort4 ov;
            ov.x = f2b(o[0]); ov.y = f2b(o[1]); ov.z = f2b(o[2]); ov.w = f2b(o[3]);
            *(ushort4*)(h + (size_t)m * 256 + col) = ov;
        }
    }
}

// Uh = h @ BuT^T. K=256, 4 double-buffered steps (1 barrier each). Grid 1252. 48KB.
__global__ __launch_bounds__(256) void k_mg_uh(
    const u16* __restrict__ A, const u16* __restrict__ BT, u16* __restrict__ C) {
    __shared__ u16 As0[8192], As1[8192], Bs0[4096], Bs1[4096];
    GT_PROLOG()
    f32x4 acc[4][2]; ACC_INIT(acc)
    uint4 ra[4], rb[2];
    ldA(A, m0, 256, 0, tid, ra); ldB(BT, n0, 256, 0, tid, rb);
    wrA(As0, tid, ra); wrB(Bs0, tid, rb);
    __syncthreads();
    ldA(A, m0, 256, 64, tid, ra); ldB(BT, n0, 256, 64, tid, rb);
    mma_step(As0, Bs0, acc, lane, wr, wc);
    wrA(As1, tid, ra); wrB(Bs1, tid, rb);
    __syncthreads();
    ldA(A, m0, 256, 128, tid, ra); ldB(BT, n0, 256, 128, tid, rb);
    mma_step(As1, Bs1, acc, lane, wr, wc);
    wrA(As0, tid, ra); wrB(Bs0, tid, rb);
    __syncthreads();
    ldA(A, m0, 256, 192, tid, ra); ldB(BT, n0, 256, 192, tid, rb);
    mma_step(As0, Bs0, acc, lane, wr, wc);
    wrA(As1, tid, ra); wrB(Bs1, tid, rb);
    __syncthreads();
    mma_step(As1, Bs1, acc, lane, wr, wc);
    #pragma unroll
    for (int mi = 0; mi < 4; ++mi) {
        int m = (int)m0 + row_l + (mi << 4);
        if (m >= 40000) continue;
        #pragma unroll
        for (int ni = 0; ni < 2; ++ni) {
            int col = (int)n0 + col_l + (ni << 4);
            ushort4 o;
            o.x = f2b(acc[mi][ni][0]); o.y = f2b(acc[mi][ni][1]);
            o.z = f2b(acc[mi][ni][2]); o.w = f2b(acc[mi][ni][3]);
            *(ushort4*)(C + (size_t)m * 256 + col) = o;
        }
    }
}

// PrU = x @ BrT^T + urb. K=128, 2 dbuf steps. Grid 1252. 48KB.
__global__ __launch_bounds__(256) void k_mg_p(
    const u16* __restrict__ x, const u16* __restrict__ BrT,
    const float* __restrict__ urb, u16* __restrict__ PrU) {
    __shared__ u16 As0[8192], As1[8192], Bs0[4096], Bs1[4096];
    GT_PROLOG()
    f32x4 acc[4][2]; ACC_INIT(acc)
    uint4 ra[4], rb[2];
    ldA(x, m0, 128, 0, tid, ra); ldB(BrT, n0, 128, 0, tid, rb);
    wrA(As0, tid, ra); wrB(Bs0, tid, rb);
    __syncthreads();
    ldA(x, m0, 128, 64, tid, ra); ldB(BrT, n0, 128, 64, tid, rb);
    mma_step(As0, Bs0, acc, lane, wr, wc);
    wrA(As1, tid, ra); wrB(Bs1, tid, rb);
    __syncthreads();
    mma_step(As1, Bs1, acc, lane, wr, wc);
    #pragma unroll
    for (int mi = 0; mi < 4; ++mi) {
        int m = (int)m0 + row_l + (mi << 4);
        if (m >= 40000) continue;
        #pragma unroll
        for (int ni = 0; ni < 2; ++ni) {
            int col = (int)n0 + col_l + (ni << 4);
            float4 ub = *(const float4*)(urb + col);
            ushort4 o;
            o.x = f2b(acc[mi][ni][0] + ub.x); o.y = f2b(acc[mi][ni][1] + ub.y);
            o.z = f2b(acc[mi][ni][2] + ub.z); o.w = f2b(acc[mi][ni][3] + ub.w);
            *(ushort4*)(PrU + (size_t)m * 256 + col) = o;
        }
    }
}

// Depth-1: h = sigm(x@Bzx+bz)*tanh(x@Bhx+bh). x resident in As1/As2; B swapped.
// Grid 1252. 48KB, 3 barriers.
__global__ __launch_bounds__(256) void k_d1(
    const u16* __restrict__ x, const u16* __restrict__ BzT,
    const u16* __restrict__ BhT, const float* __restrict__ bz,
    const float* __restrict__ bh, u16* __restrict__ h) {
    __shared__ u16 As1[8192], As2[8192], Bs1[4096], Bs2[4096];
    GT_PROLOG()
    f32x4 aZ[4][2], aH[4][2]; ACC_INIT(aZ) ACC_INIT(aH)
    uint4 ra1[4], ra2[4], rb1[2], rb2[2];
    ldA(x, m0, 128, 0, tid, ra1); ldA(x, m0, 128, 64, tid, ra2);
    ldB(BzT, n0, 384, 0, tid, rb1); ldB(BzT, n0, 384, 64, tid, rb2);
    wrA(As1, tid, ra1); wrA(As2, tid, ra2); wrB(Bs1, tid, rb1); wrB(Bs2, tid, rb2);
    __syncthreads();
    ldB(BhT, n0, 384, 0, tid, rb1); ldB(BhT, n0, 384, 64, tid, rb2);
    mma_step(As1, Bs1, aZ, lane, wr, wc); mma_step(As2, Bs2, aZ, lane, wr, wc);
    __syncthreads();
    wrB(Bs1, tid, rb1); wrB(Bs2, tid, rb2);
    __syncthreads();
    mma_step(As1, Bs1, aH, lane, wr, wc); mma_step(As2, Bs2, aH, lane, wr, wc);
    #pragma unroll
    for (int mi = 0; mi < 4; ++mi) {
        int m = (int)m0 + row_l + (mi << 4);
        if (m >= 40000) continue;
        #pragma unroll
        for (int ni = 0; ni < 2; ++ni) {
            int col = (int)n0 + col_l + (ni << 4);
            float4 vz = *(const float4*)(bz + col);
            float4 vh = *(const float4*)(bh + col);
            float r[4];
            r[0] = sigm(aZ[mi][ni][0] + vz.x) * tanh_(aH[mi][ni][0] + vh.x);
            r[1] = sigm(aZ[mi][ni][1] + vz.y) * tanh_(aH[mi][ni][1] + vh.y);
            r[2] = sigm(aZ[mi][ni][2] + vz.z) * tanh_(aH[mi][ni][2] + vh.z);
            r[3] = sigm(aZ[mi][ni][3] + vz.w) * tanh_(aH[mi][ni][3] + vh.w);
            if (m == 0) { r[0] = r[1] = r[2] = r[3] = 0.0f; }
            ushort4 o;
            o.x = f2b(r[0]); o.y = f2b(r[1]); o.z = f2b(r[2]); o.w = f2b(r[3]);
            *(ushort4*)(h + (size_t)m * 256 + col) = o;
        }
    }
}

// out = gelu([fb|nei]@Bo + bo). K=384, 6 dbuf steps. Grid 628. 48KB. f32, row0 masked.
__global__ __launch_bounds__(256) void k_mg_out(
    const u16* __restrict__ fb, const u16* __restrict__ nei,
    const u16* __restrict__ BoT, const float* __restrict__ bo,
    float* __restrict__ out) {
    __shared__ u16 As0[8192], As1[8192], Bs0[4096], Bs1[4096];
    GT_PROLOG()
    f32x4 acc[4][2]; ACC_INIT(acc)
    uint4 ra[4], rb[2];
    ldA(fb, m0, 128, 0, tid, ra); ldB(BoT, n0, 384, 0, tid, rb);
    wrA(As0, tid, ra); wrB(Bs0, tid, rb);
    __syncthreads();
    ldA(fb, m0, 128, 64, tid, ra); ldB(BoT, n0, 384, 64, tid, rb);
    mma_step(As0, Bs0, acc, lane, wr, wc);
    wrA(As1, tid, ra); wrB(Bs1, tid, rb);
    __syncthreads();
    ldA(nei, m0, 256, 0, tid, ra); ldB(BoT, n0, 384, 128, tid, rb);
    mma_step(As1, Bs1, acc, lane, wr, wc);
    wrA(As0, tid, ra); wrB(Bs0, tid, rb);
    __syncthreads();
    ldA(nei, m0, 256, 64, tid, ra); ldB(BoT, n0, 384, 192, tid, rb);
    mma_step(As0, Bs0, acc, lane, wr, wc);
    wrA(As1, tid, ra); wrB(Bs1, tid, rb);
    __syncthreads();
    ldA(nei, m0, 256, 128, tid, ra); ldB(BoT, n0, 384, 256, tid, rb);
    mma_step(As1, Bs1, acc, lane, wr, wc);
    wrA(As0, tid, ra); wrB(Bs0, tid, rb);
    __syncthreads();
    ldA(nei, m0, 256, 192, tid, ra); ldB(BoT, n0, 384, 320, tid, rb);
    mma_step(As0, Bs0, acc, lane, wr, wc);
    wrA(As1, tid, ra); wrB(Bs1, tid, rb);
    __syncthreads();
    mma_step(As1, Bs1, acc, lane, wr, wc);
    #pragma unroll
    for (int mi = 0; mi < 4; ++mi) {
        int m = (int)m0 + row_l + (mi << 4);
        if (m >= 20000) continue;
        #pragma unroll
        for (int ni = 0; ni < 2; ++ni) {
            int col = (int)n0 + col_l + (ni << 4);
            float4 vb = *(const float4*)(bo + col);
            float4 o;
            o.x = gelu_(acc[mi][ni][0] + vb.x);
            o.y = gelu_(acc[mi][ni][1] + vb.y);
            o.z = gelu_(acc[mi][ni][2] + vb.z);
            o.w = gelu_(acc[mi][ni][3] + vb.w);
            if (m == 0) { o.x = o.y = o.z = o.w = 0.0f; }
            *(float4*)(out + (size_t)m * 256 + col) = o;
        }
    }
}

// ---------------------------------------------------------------------------
// sumh/sumgh gather. Grid 5000x256.
__global__ __launch_bounds__(256) void k_gather_edge(
    const u16* __restrict__ h, const u16* __restrict__ Uh,
    const u16* __restrict__ PrU, const int* __restrict__ bgraph,
    u16* __restrict__ sumh, u16* __restrict__ sumgh) {
    int e = (blockIdx.x << 3) + (threadIdx.x >> 5);
    int c = (threadIdx.x & 31) << 3;
    size_t o = (size_t)e * 256 + c;
    float pr[8];
    u4tof8(*(const uint4*)(PrU + o), pr);
    float sh[8] = {}, sg[8] = {};
    #pragma unroll
    for (int j = 0; j < 6; ++j) {
        int b = bgraph[e * 6 + j];
        float hv[8], uv[8];
        u4tof8(*(const uint4*)(h  + (size_t)b * 256 + c), hv);
        u4tof8(*(const uint4*)(Uh + (size_t)b * 256 + c), uv);
        #pragma unroll
        for (int q = 0; q < 8; ++q) {
            sh[q] += hv[q];
            sg[q] += sigm(pr[q] + uv[q]) * hv[q];
        }
    }
    *(uint4*)(sumh  + o) = f8tou4(sh);
    *(uint4*)(sumgh + o) = f8tou4(sg);
}

// nei[n] = bf16(sum_j h[agraph[n][j]]). Grid 2500x256.
__global__ __launch_bounds__(256) void k_gather_node(
    const u16* __restrict__ h, const int* __restrict__ agraph,
    u16* __restrict__ nei) {
    int n = (blockIdx.x << 3) + (threadIdx.x >> 5);
    int c = (threadIdx.x & 31) << 3;
    float s[8] = {};
    #pragma unroll
    for (int j = 0; j < 6; ++j) {
        int a = agraph[n * 6 + j];
        float hv[8];
        u4tof8(*(const uint4*)(h + (size_t)a * 256 + c), hv);
        #pragma unroll
        for (int q = 0; q < 8; ++q) s[q] += hv[q];
    }
    *(uint4*)(nei + (size_t)n * 256 + c) = f8tou4(s);
}

// ---------------------------------------------------------------------------
extern "C" void kernel_launch(void* const* d_in, const int* in_sizes, int n_in,
                              void* d_out, int out_size, void* d_ws, size_t ws_size,
                              hipStream_t stream) {
    if (ws_size < WS_BYTES) return;

    const float* fnode  = (const float*)d_in[0];
    const float* fmess  = (const float*)d_in[1];
    const int*   agraph = (const int*)d_in[2];
    const int*   bgraph = (const int*)d_in[3];
    const float* Wz  = (const float*)d_in[4];
    const float* bz  = (const float*)d_in[5];
    const float* Wr  = (const float*)d_in[6];
    const float* Ur  = (const float*)d_in[7];
    const float* urb = (const float*)d_in[8];
    const float* Wh  = (const float*)d_in[9];
    const float* bh  = (const float*)d_in[10];
    const float* Wo  = (const float*)d_in[11];
    const float* bo  = (const float*)d_in[12];

    char* base = (char*)d_ws;
    u16* x     = (u16*)(base + OB_X);
    u16* fb    = (u16*)(base + OB_FB);
    u16* PrU   = (u16*)(base + OB_PRU);
    u16* h     = (u16*)(base + OB_H);
    u16* Uh    = (u16*)(base + OB_UH);
    u16* nei   = (u16*)(base + OB_UH);   // overlay after depth loop
    u16* sumh  = (u16*)(base + OB_SH);
    u16* sumgh = (u16*)(base + OB_SGH);
    u16* BzT   = (u16*)(base + OB_BZ);
    u16* BhT   = (u16*)(base + OB_BH);
    u16* BuT   = (u16*)(base + OB_BU);
    u16* BrT   = (u16*)(base + OB_BR);
    u16* BoT   = (u16*)(base + OB_BO);
    float* out = (float*)d_out;

    hipLaunchKernelGGL(k_repack, dim3(384), dim3(256), 0, stream,
                       Wz, Wr, Ur, Wh, Wo, BzT, BhT, BuT, BrT, BoT);
    hipLaunchKernelGGL(k_build_x, dim3(20000), dim3(256), 0, stream, fnode, fmess, x);
    hipLaunchKernelGGL(k_build_fb, dim3(10000), dim3(256), 0, stream, fnode, fb);
    hipLaunchKernelGGL(k_mg_p, dim3(1252), dim3(256), 0, stream, x, BrT, urb, PrU);
    hipLaunchKernelGGL(k_d1,   dim3(1252), dim3(256), 0, stream, x, BzT, BhT, bz, bh, h);
    for (int d = 1; d < 4; ++d) {
        hipLaunchKernelGGL(k_mg_uh, dim3(1252), dim3(256), 0, stream, h, BuT, Uh);
        hipLaunchKernelGGL(k_gather_edge, dim3(5000), dim3(256), 0, stream,
                           h, Uh, PrU, bgraph, sumh, sumgh);
        hipLaunchKernelGGL(k_mg_fused, dim3(1252), dim3(256), 0, stream,
                           x, sumh, sumgh, BzT, BhT, bz, bh, h);
    }
    hipLaunchKernelGGL(k_gather_node, dim3(2500), dim3(256), 0, stream, h, agraph, nei);
    hipLaunchKernelGGL(k_mg_out, dim3(628), dim3(256), 0, stream, fb, nei, BoT, bo, out);
}

// Round 9
// 609.981 us; speedup vs baseline: 1.2803x; 1.1117x over previous
//
#include <hip/hip_runtime.h>
#include <cstddef>
#include <cstdint>

typedef unsigned short u16;
typedef unsigned int   u32;
typedef __bf16  bf16x8 __attribute__((ext_vector_type(8)));
typedef float   f32x4  __attribute__((ext_vector_type(4)));

#define DEV __device__ __forceinline__

DEV float b2f(u16 u) { union { u32 i; float f; } c; c.i = ((u32)u) << 16; return c.f; }
DEV u16 f2b(float x) { union { float f; u32 i; } c; c.f = x; u32 b = c.i;
                       return (u16)((b + 0x7FFFu + ((b >> 16) & 1u)) >> 16); }
DEV float sigm(float x)  { return 1.0f / (1.0f + __expf(-x)); }
DEV float tanh_(float x) { return 1.0f - 2.0f / (1.0f + __expf(2.0f * x)); }
DEV float gelu_(float x) { return 0.5f * x * (1.0f + erff(x * 0.70710678118654752f)); }

DEV void u4tof8(uint4 v, float* f) {
    f[0] = b2f((u16)(v.x & 0xFFFF)); f[1] = b2f((u16)(v.x >> 16));
    f[2] = b2f((u16)(v.y & 0xFFFF)); f[3] = b2f((u16)(v.y >> 16));
    f[4] = b2f((u16)(v.z & 0xFFFF)); f[5] = b2f((u16)(v.z >> 16));
    f[6] = b2f((u16)(v.w & 0xFFFF)); f[7] = b2f((u16)(v.w >> 16));
}
DEV uint4 f8tou4(const float* f) {
    uint4 v;
    v.x = (u32)f2b(f[0]) | ((u32)f2b(f[1]) << 16);
    v.y = (u32)f2b(f[2]) | ((u32)f2b(f[3]) << 16);
    v.z = (u32)f2b(f[4]) | ((u32)f2b(f[5]) << 16);
    v.w = (u32)f2b(f[6]) | ((u32)f2b(f[7]) << 16);
    return v;
}

// ---- workspace byte offsets; total 118,546,432 B (fits: 144,113,664 proven) ----
#define OB_X     0ull            // x  [40000][128] bf16
#define OB_FB    10240000ull     // fb [20000][128] bf16
#define OB_PRU   15360000ull     // PrU [40000][256] bf16 (= x@Wr^T + urb)
#define OB_H     35840000ull     // h   [40000][256] bf16
#define OB_UH    56320000ull     // Uh  [40000][256] bf16 ; nei overlays after loop
#define OB_SH    76800000ull     // sumh  [40000][256] bf16
#define OB_SGH   97280000ull     // sumgh [40000][256] bf16
#define OB_BZ    117760000ull    // BzT [256][384] bf16 : Wz[:, :111]|pad|Wz[:,111:]
#define OB_BH    117956608ull    // BhT [256][384] bf16
#define OB_BU    118153216ull    // BuT [256][256] bf16
#define OB_BR    118284288ull    // BrT [256][128] bf16 (Wr, K-pad)
#define OB_BO    118349824ull    // BoT [256][384] bf16 : Wo[:, :98]|pad|Wo[:,98:]
#define WS_BYTES 118546432ull

// Occupancy control for MFMA kernels: the scheduler's default behavior is to
// CHASE max occupancy and spill registers to get it (R5-R8: VGPR capped at
// 64-88, 190-340MB scratch traffic). launch_bounds' 2nd arg only RAISES the
// floor (R7 made it worse). amdgpu_waves_per_eu(min,max) bounds the TARGET:
// min=2 -> register budget 256; max=3 -> stop chasing past 3 waves/EU
// (= 3 blocks/CU that 48KB LDS allows). Accumulators stay in registers.
#define MFMA_ATTR __attribute__((amdgpu_waves_per_eu(2, 3)))

// ---------------------------------------------------------------------------
// Weight repack -> [N][K] bf16. Grid 384x256.
__global__ __launch_bounds__(256) void k_repack(
    const float* __restrict__ Wz, const float* __restrict__ Wr,
    const float* __restrict__ Ur, const float* __restrict__ Wh,
    const float* __restrict__ Wo,
    u16* __restrict__ BzT, u16* __restrict__ BhT, u16* __restrict__ BuT,
    u16* __restrict__ BrT, u16* __restrict__ BoT) {
    int idx = blockIdx.x * 256 + threadIdx.x;   // 0..98303
    {
        int n = idx / 384, k = idx % 384;
        float vz, vh, vo;
        if (k < 111)      { vz = Wz[n * 367 + k];      vh = Wh[n * 367 + k]; }
        else if (k < 128) { vz = 0.0f;                 vh = 0.0f; }
        else              { vz = Wz[n * 367 + k - 17]; vh = Wh[n * 367 + k - 17]; }
        if (k < 98)       vo = Wo[n * 354 + k];
        else if (k < 128) vo = 0.0f;
        else              vo = Wo[n * 354 + k - 30];
        BzT[idx] = f2b(vz); BhT[idx] = f2b(vh); BoT[idx] = f2b(vo);
    }
    if (idx < 65536) BuT[idx] = f2b(Ur[idx]);
    if (idx < 32768) {
        int n = idx >> 7, k = idx & 127;
        BrT[idx] = f2b(k < 111 ? Wr[n * 111 + k] : 0.0f);
    }
}

// x[e][c] (bf16, [40000][128], zero pad). Grid 20000x256 (2 edges/block).
__global__ __launch_bounds__(256) void k_build_x(const float* __restrict__ fnode,
                                                 const float* __restrict__ fmess,
                                                 u16* __restrict__ x) {
    int e = (blockIdx.x << 1) + (threadIdx.x >> 7);
    int c = threadIdx.x & 127;
    int src = (int)fmess[(size_t)e * 15];
    float v = 0.0f;
    if (c < 98)       v = fnode[(size_t)src * 98 + c];
    else if (c < 111) v = fmess[(size_t)e * 15 + 2 + (c - 98)];
    x[(size_t)e * 128 + c] = f2b(v);
}

// fb [20000][128] bf16 zero-padded. Grid 10000x256.
__global__ __launch_bounds__(256) void k_build_fb(const float* __restrict__ fnode,
                                                  u16* __restrict__ fb) {
    int idx = blockIdx.x * 256 + threadIdx.x;
    int n = idx >> 7, c = idx & 127;
    fb[idx] = f2b(c < 98 ? fnode[(size_t)n * 98 + c] : 0.0f);
}

// ---------------------------------------------------------------------------
// Template: BM=128, BN=64, BK=64. 256 threads = 4 waves (2M x 2N),
// wave tile 64x32, acc[4][2]. LDS swizzle: byte ^= (row&7)<<4. 48KB LDS/block.
DEV void ldA(const u16* __restrict__ g, size_t row0, int ld, int k0, int tid, uint4* v) {
    #pragma unroll
    for (int it = 0; it < 4; ++it) {
        int r = it * 32 + (tid >> 3);
        int c = (tid & 7) << 3;
        v[it] = *(const uint4*)(g + (row0 + (size_t)r) * ld + k0 + c);
    }
}
DEV void ldB(const u16* __restrict__ g, size_t row0, int ld, int k0, int tid, uint4* v) {
    #pragma unroll
    for (int it = 0; it < 2; ++it) {
        int r = it * 32 + (tid >> 3);
        int c = (tid & 7) << 3;
        v[it] = *(const uint4*)(g + (row0 + (size_t)r) * ld + k0 + c);
    }
}
DEV void wrA(u16* s, int tid, const uint4* v) {
    #pragma unroll
    for (int it = 0; it < 4; ++it) {
        int r = it * 32 + (tid >> 3);
        int c = (tid & 7) << 3;
        int byte = (((r << 6) + c) << 1) ^ ((r & 7) << 4);
        *(uint4*)((char*)s + byte) = v[it];
    }
}
DEV void wrB(u16* s, int tid, const uint4* v) {
    #pragma unroll
    for (int it = 0; it < 2; ++it) {
        int r = it * 32 + (tid >> 3);
        int c = (tid & 7) << 3;
        int byte = (((r << 6) + c) << 1) ^ ((r & 7) << 4);
        *(uint4*)((char*)s + byte) = v[it];
    }
}
// Swapped-operand MFMA: acc[i][j][q] = C[row_l+16i][col_l+16j+q]
DEV void mma_step(const u16* As, const u16* Bs, f32x4 acc[4][2], int lane, int wr, int wc) {
    int rb = (wr << 6) + (lane & 15);
    int cb = (wc << 5) + (lane & 15);
    int ko = (lane >> 4) << 3;
    #pragma unroll
    for (int kh = 0; kh < 2; ++kh) {
        bf16x8 a[4], b[2];
        #pragma unroll
        for (int i = 0; i < 4; ++i) {
            int ar = rb + (i << 4);
            a[i] = *(const bf16x8*)((const char*)As +
                   ((((ar << 6) + (kh << 5) + ko) << 1) ^ ((ar & 7) << 4)));
        }
        #pragma unroll
        for (int j = 0; j < 2; ++j) {
            int br = cb + (j << 4);
            b[j] = *(const bf16x8*)((const char*)Bs +
                   ((((br << 6) + (kh << 5) + ko) << 1) ^ ((br & 7) << 4)));
        }
        #pragma unroll
        for (int i = 0; i < 4; ++i)
            #pragma unroll
            for (int j = 0; j < 2; ++j)
                acc[i][j] = __builtin_amdgcn_mfma_f32_16x16x32_bf16(b[j], a[i], acc[i][j], 0, 0, 0);
    }
}

#define GT_PROLOG()                                            \
    int tid = threadIdx.x, lane = tid & 63, w = tid >> 6;      \
    int wr = w >> 1, wc = w & 1;                               \
    int bm = blockIdx.x >> 2, bn = blockIdx.x & 3;             \
    size_t m0 = (size_t)bm << 7; size_t n0 = (size_t)(bn << 6);\
    int row_l = (wr << 6) + (lane & 15);                       \
    int col_l = (wc << 5) + ((lane >> 4) << 2);

#define ACC_INIT(A)                                            \
    { f32x4 zz = {0.f, 0.f, 0.f, 0.f};                         \
      _Pragma("unroll") for (int i = 0; i < 4; ++i)            \
      _Pragma("unroll") for (int j = 0; j < 2; ++j) A[i][j] = zz; }

// ---------------------------------------------------------------------------
// Fused GRU step: z=sigm([x|sumh]@Bz+bz); pre=tanh([x|sumgh]@Bh+bh);
// h=((1-z)*sumh+z*pre)*emask. 6 static K=64 steps, dual acc. Grid 1252. 48KB.
__global__ __launch_bounds__(256) MFMA_ATTR void k_mg_fused(
    const u16* __restrict__ x, const u16* __restrict__ sumh,
    const u16* __restrict__ sumgh, const u16* __restrict__ BzT,
    const u16* __restrict__ BhT, const float* __restrict__ bz,
    const float* __restrict__ bh, u16* __restrict__ h) {
    __shared__ u16 As1[8192], As2[8192], Bs1[4096], Bs2[4096];
    GT_PROLOG()
    f32x4 aZ[4][2], aH[4][2]; ACC_INIT(aZ) ACC_INIT(aH)
    uint4 ra1[4], ra2[4], rb1[2], rb2[2];
    // step 0: A=x[k0], B=Bz[k0]/Bh[k0]  (As2 unused in x phase)
    ldA(x, m0, 128, 0, tid, ra1); ldB(BzT, n0, 384, 0, tid, rb1); ldB(BhT, n0, 384, 0, tid, rb2);
    wrA(As1, tid, ra1); wrB(Bs1, tid, rb1); wrB(Bs2, tid, rb2);
    __syncthreads();
    ldA(x, m0, 128, 64, tid, ra1); ldB(BzT, n0, 384, 64, tid, rb1); ldB(BhT, n0, 384, 64, tid, rb2);
    mma_step(As1, Bs1, aZ, lane, wr, wc); mma_step(As1, Bs2, aH, lane, wr, wc);
    __syncthreads();
    // step 1: A=x[k64]
    wrA(As1, tid, ra1); wrB(Bs1, tid, rb1); wrB(Bs2, tid, rb2);
    __syncthreads();
    ldA(sumh, m0, 256, 0, tid, ra1); ldA(sumgh, m0, 256, 0, tid, ra2);
    ldB(BzT, n0, 384, 128, tid, rb1); ldB(BhT, n0, 384, 128, tid, rb2);
    mma_step(As1, Bs1, aZ, lane, wr, wc); mma_step(As1, Bs2, aH, lane, wr, wc);
    __syncthreads();
    // steps 2..5: A1=sumh[k], A2=sumgh[k], B=Bz/Bh[128+k]
    #define F_STEP(KS, LAST)                                                     \
    {                                                                            \
        wrA(As1, tid, ra1); wrA(As2, tid, ra2);                                  \
        wrB(Bs1, tid, rb1); wrB(Bs2, tid, rb2);                                  \
        __syncthreads();                                                         \
        if (!(LAST)) {                                                           \
            ldA(sumh, m0, 256, (KS) + 64, tid, ra1);                             \
            ldA(sumgh, m0, 256, (KS) + 64, tid, ra2);                            \
            ldB(BzT, n0, 384, (KS) + 192, tid, rb1);                             \
            ldB(BhT, n0, 384, (KS) + 192, tid, rb2);                             \
        }                                                                        \
        mma_step(As1, Bs1, aZ, lane, wr, wc);                                    \
        mma_step(As2, Bs2, aH, lane, wr, wc);                                    \
        if (!(LAST)) __syncthreads();                                            \
    }
    F_STEP(0, 0) F_STEP(64, 0) F_STEP(128, 0) F_STEP(192, 1)
    #undef F_STEP
    #pragma unroll
    for (int mi = 0; mi < 4; ++mi) {
        int m = (int)m0 + row_l + (mi << 4);
        if (m >= 40000) continue;
        #pragma unroll
        for (int ni = 0; ni < 2; ++ni) {
            int col = (int)n0 + col_l + (ni << 4);
            float4 vz = *(const float4*)(bz + col);
            float4 vh = *(const float4*)(bh + col);
            ushort4 sh4 = *(const ushort4*)(sumh + (size_t)m * 256 + col);
            float shv[4] = {b2f(sh4.x), b2f(sh4.y), b2f(sh4.z), b2f(sh4.w)};
            float bzv[4] = {vz.x, vz.y, vz.z, vz.w};
            float bhv[4] = {vh.x, vh.y, vh.z, vh.w};
            float o[4];
            #pragma unroll
            for (int q = 0; q < 4; ++q) {
                float z   = sigm(aZ[mi][ni][q] + bzv[q]);
                float pre = tanh_(aH[mi][ni][q] + bhv[q]);
                o[q] = (1.0f - z) * shv[q] + z * pre;
            }
            if (m == 0) { o[0] = o[1] = o[2] = o[3] = 0.0f; }
            ushort4 ov;
            ov.x = f2b(o[0]); ov.y = f2b(o[1]); ov.z = f2b(o[2]); ov.w = f2b(o[3]);
            *(ushort4*)(h + (size_t)m * 256 + col) = ov;
        }
    }
}

// Uh = h @ BuT^T. K=256, 4 double-buffered steps (1 barrier each). Grid 1252. 48KB.
__global__ __launch_bounds__(256) MFMA_ATTR void k_mg_uh(
    const u16* __restrict__ A, const u16* __restrict__ BT, u16* __restrict__ C) {
    __shared__ u16 As0[8192], As1[8192], Bs0[4096], Bs1[4096];
    GT_PROLOG()
    f32x4 acc[4][2]; ACC_INIT(acc)
    uint4 ra[4], rb[2];
    ldA(A, m0, 256, 0, tid, ra); ldB(BT, n0, 256, 0, tid, rb);
    wrA(As0, tid, ra); wrB(Bs0, tid, rb);
    __syncthreads();
    ldA(A, m0, 256, 64, tid, ra); ldB(BT, n0, 256, 64, tid, rb);
    mma_step(As0, Bs0, acc, lane, wr, wc);
    wrA(As1, tid, ra); wrB(Bs1, tid, rb);
    __syncthreads();
    ldA(A, m0, 256, 128, tid, ra); ldB(BT, n0, 256, 128, tid, rb);
    mma_step(As1, Bs1, acc, lane, wr, wc);
    wrA(As0, tid, ra); wrB(Bs0, tid, rb);
    __syncthreads();
    ldA(A, m0, 256, 192, tid, ra); ldB(BT, n0, 256, 192, tid, rb);
    mma_step(As0, Bs0, acc, lane, wr, wc);
    wrA(As1, tid, ra); wrB(Bs1, tid, rb);
    __syncthreads();
    mma_step(As1, Bs1, acc, lane, wr, wc);
    #pragma unroll
    for (int mi = 0; mi < 4; ++mi) {
        int m = (int)m0 + row_l + (mi << 4);
        if (m >= 40000) continue;
        #pragma unroll
        for (int ni = 0; ni < 2; ++ni) {
            int col = (int)n0 + col_l + (ni << 4);
            ushort4 o;
            o.x = f2b(acc[mi][ni][0]); o.y = f2b(acc[mi][ni][1]);
            o.z = f2b(acc[mi][ni][2]); o.w = f2b(acc[mi][ni][3]);
            *(ushort4*)(C + (size_t)m * 256 + col) = o;
        }
    }
}

// PrU = x @ BrT^T + urb. K=128, 2 dbuf steps. Grid 1252. 48KB.
__global__ __launch_bounds__(256) MFMA_ATTR void k_mg_p(
    const u16* __restrict__ x, const u16* __restrict__ BrT,
    const float* __restrict__ urb, u16* __restrict__ PrU) {
    __shared__ u16 As0[8192], As1[8192], Bs0[4096], Bs1[4096];
    GT_PROLOG()
    f32x4 acc[4][2]; ACC_INIT(acc)
    uint4 ra[4], rb[2];
    ldA(x, m0, 128, 0, tid, ra); ldB(BrT, n0, 128, 0, tid, rb);
    wrA(As0, tid, ra); wrB(Bs0, tid, rb);
    __syncthreads();
    ldA(x, m0, 128, 64, tid, ra); ldB(BrT, n0, 128, 64, tid, rb);
    mma_step(As0, Bs0, acc, lane, wr, wc);
    wrA(As1, tid, ra); wrB(Bs1, tid, rb);
    __syncthreads();
    mma_step(As1, Bs1, acc, lane, wr, wc);
    #pragma unroll
    for (int mi = 0; mi < 4; ++mi) {
        int m = (int)m0 + row_l + (mi << 4);
        if (m >= 40000) continue;
        #pragma unroll
        for (int ni = 0; ni < 2; ++ni) {
            int col = (int)n0 + col_l + (ni << 4);
            float4 ub = *(const float4*)(urb + col);
            ushort4 o;
            o.x = f2b(acc[mi][ni][0] + ub.x); o.y = f2b(acc[mi][ni][1] + ub.y);
            o.z = f2b(acc[mi][ni][2] + ub.z); o.w = f2b(acc[mi][ni][3] + ub.w);
            *(ushort4*)(PrU + (size_t)m * 256 + col) = o;
        }
    }
}

// Depth-1: h = sigm(x@Bzx+bz)*tanh(x@Bhx+bh). x resident in As1/As2; B swapped.
// Grid 1252. 48KB, 3 barriers.
__global__ __launch_bounds__(256) MFMA_ATTR void k_d1(
    const u16* __restrict__ x, const u16* __restrict__ BzT,
    const u16* __restrict__ BhT, const float* __restrict__ bz,
    const float* __restrict__ bh, u16* __restrict__ h) {
    __shared__ u16 As1[8192], As2[8192], Bs1[4096], Bs2[4096];
    GT_PROLOG()
    f32x4 aZ[4][2], aH[4][2]; ACC_INIT(aZ) ACC_INIT(aH)
    uint4 ra1[4], ra2[4], rb1[2], rb2[2];
    ldA(x, m0, 128, 0, tid, ra1); ldA(x, m0, 128, 64, tid, ra2);
    ldB(BzT, n0, 384, 0, tid, rb1); ldB(BzT, n0, 384, 64, tid, rb2);
    wrA(As1, tid, ra1); wrA(As2, tid, ra2); wrB(Bs1, tid, rb1); wrB(Bs2, tid, rb2);
    __syncthreads();
    ldB(BhT, n0, 384, 0, tid, rb1); ldB(BhT, n0, 384, 64, tid, rb2);
    mma_step(As1, Bs1, aZ, lane, wr, wc); mma_step(As2, Bs2, aZ, lane, wr, wc);
    __syncthreads();
    wrB(Bs1, tid, rb1); wrB(Bs2, tid, rb2);
    __syncthreads();
    mma_step(As1, Bs1, aH, lane, wr, wc); mma_step(As2, Bs2, aH, lane, wr, wc);
    #pragma unroll
    for (int mi = 0; mi < 4; ++mi) {
        int m = (int)m0 + row_l + (mi << 4);
        if (m >= 40000) continue;
        #pragma unroll
        for (int ni = 0; ni < 2; ++ni) {
            int col = (int)n0 + col_l + (ni << 4);
            float4 vz = *(const float4*)(bz + col);
            float4 vh = *(const float4*)(bh + col);
            float r[4];
            r[0] = sigm(aZ[mi][ni][0] + vz.x) * tanh_(aH[mi][ni][0] + vh.x);
            r[1] = sigm(aZ[mi][ni][1] + vz.y) * tanh_(aH[mi][ni][1] + vh.y);
            r[2] = sigm(aZ[mi][ni][2] + vz.z) * tanh_(aH[mi][ni][2] + vh.z);
            r[3] = sigm(aZ[mi][ni][3] + vz.w) * tanh_(aH[mi][ni][3] + vh.w);
            if (m == 0) { r[0] = r[1] = r[2] = r[3] = 0.0f; }
            ushort4 o;
            o.x = f2b(r[0]); o.y = f2b(r[1]); o.z = f2b(r[2]); o.w = f2b(r[3]);
            *(ushort4*)(h + (size_t)m * 256 + col) = o;
        }
    }
}

// out = gelu([fb|nei]@Bo + bo). K=384, 6 dbuf steps. Grid 628. 48KB. f32, row0 masked.
__global__ __launch_bounds__(256) MFMA_ATTR void k_mg_out(
    const u16* __restrict__ fb, const u16* __restrict__ nei,
    const u16* __restrict__ BoT, const float* __restrict__ bo,
    float* __restrict__ out) {
    __shared__ u16 As0[8192], As1[8192], Bs0[4096], Bs1[4096];
    GT_PROLOG()
    f32x4 acc[4][2]; ACC_INIT(acc)
    uint4 ra[4], rb[2];
    ldA(fb, m0, 128, 0, tid, ra); ldB(BoT, n0, 384, 0, tid, rb);
    wrA(As0, tid, ra); wrB(Bs0, tid, rb);
    __syncthreads();
    ldA(fb, m0, 128, 64, tid, ra); ldB(BoT, n0, 384, 64, tid, rb);
    mma_step(As0, Bs0, acc, lane, wr, wc);
    wrA(As1, tid, ra); wrB(Bs1, tid, rb);
    __syncthreads();
    ldA(nei, m0, 256, 0, tid, ra); ldB(BoT, n0, 384, 128, tid, rb);
    mma_step(As1, Bs1, acc, lane, wr, wc);
    wrA(As0, tid, ra); wrB(Bs0, tid, rb);
    __syncthreads();
    ldA(nei, m0, 256, 64, tid, ra); ldB(BoT, n0, 384, 192, tid, rb);
    mma_step(As0, Bs0, acc, lane, wr, wc);
    wrA(As1, tid, ra); wrB(Bs1, tid, rb);
    __syncthreads();
    ldA(nei, m0, 256, 128, tid, ra); ldB(BoT, n0, 384, 256, tid, rb);
    mma_step(As1, Bs1, acc, lane, wr, wc);
    wrA(As0, tid, ra); wrB(Bs0, tid, rb);
    __syncthreads();
    ldA(nei, m0, 256, 192, tid, ra); ldB(BoT, n0, 384, 320, tid, rb);
    mma_step(As0, Bs0, acc, lane, wr, wc);
    wrA(As1, tid, ra); wrB(Bs1, tid, rb);
    __syncthreads();
    mma_step(As1, Bs1, acc, lane, wr, wc);
    #pragma unroll
    for (int mi = 0; mi < 4; ++mi) {
        int m = (int)m0 + row_l + (mi << 4);
        if (m >= 20000) continue;
        #pragma unroll
        for (int ni = 0; ni < 2; ++ni) {
            int col = (int)n0 + col_l + (ni << 4);
            float4 vb = *(const float4*)(bo + col);
            float4 o;
            o.x = gelu_(acc[mi][ni][0] + vb.x);
            o.y = gelu_(acc[mi][ni][1] + vb.y);
            o.z = gelu_(acc[mi][ni][2] + vb.z);
            o.w = gelu_(acc[mi][ni][3] + vb.w);
            if (m == 0) { o.x = o.y = o.z = o.w = 0.0f; }
            *(float4*)(out + (size_t)m * 256 + col) = o;
        }
    }
}

// ---------------------------------------------------------------------------
// sumh/sumgh gather. Grid 5000x256.
__global__ __launch_bounds__(256) void k_gather_edge(
    const u16* __restrict__ h, const u16* __restrict__ Uh,
    const u16* __restrict__ PrU, const int* __restrict__ bgraph,
    u16* __restrict__ sumh, u16* __restrict__ sumgh) {
    int e = (blockIdx.x << 3) + (threadIdx.x >> 5);
    int c = (threadIdx.x & 31) << 3;
    size_t o = (size_t)e * 256 + c;
    float pr[8];
    u4tof8(*(const uint4*)(PrU + o), pr);
    float sh[8] = {}, sg[8] = {};
    #pragma unroll
    for (int j = 0; j < 6; ++j) {
        int b = bgraph[e * 6 + j];
        float hv[8], uv[8];
        u4tof8(*(const uint4*)(h  + (size_t)b * 256 + c), hv);
        u4tof8(*(const uint4*)(Uh + (size_t)b * 256 + c), uv);
        #pragma unroll
        for (int q = 0; q < 8; ++q) {
            sh[q] += hv[q];
            sg[q] += sigm(pr[q] + uv[q]) * hv[q];
        }
    }
    *(uint4*)(sumh  + o) = f8tou4(sh);
    *(uint4*)(sumgh + o) = f8tou4(sg);
}

// nei[n] = bf16(sum_j h[agraph[n][j]]). Grid 2500x256.
__global__ __launch_bounds__(256) void k_gather_node(
    const u16* __restrict__ h, const int* __restrict__ agraph,
    u16* __restrict__ nei) {
    int n = (blockIdx.x << 3) + (threadIdx.x >> 5);
    int c = (threadIdx.x & 31) << 3;
    float s[8] = {};
    #pragma unroll
    for (int j = 0; j < 6; ++j) {
        int a = agraph[n * 6 + j];
        float hv[8];
        u4tof8(*(const uint4*)(h + (size_t)a * 256 + c), hv);
        #pragma unroll
        for (int q = 0; q < 8; ++q) s[q] += hv[q];
    }
    *(uint4*)(nei + (size_t)n * 256 + c) = f8tou4(s);
}

// ---------------------------------------------------------------------------
extern "C" void kernel_launch(void* const* d_in, const int* in_sizes, int n_in,
                              void* d_out, int out_size, void* d_ws, size_t ws_size,
                              hipStream_t stream) {
    if (ws_size < WS_BYTES) return;

    const float* fnode  = (const float*)d_in[0];
    const float* fmess  = (const float*)d_in[1];
    const int*   agraph = (const int*)d_in[2];
    const int*   bgraph = (const int*)d_in[3];
    const float* Wz  = (const float*)d_in[4];
    const float* bz  = (const float*)d_in[5];
    const float* Wr  = (const float*)d_in[6];
    const float* Ur  = (const float*)d_in[7];
    const float* urb = (const float*)d_in[8];
    const float* Wh  = (const float*)d_in[9];
    const float* bh  = (const float*)d_in[10];
    const float* Wo  = (const float*)d_in[11];
    const float* bo  = (const float*)d_in[12];

    char* base = (char*)d_ws;
    u16* x     = (u16*)(base + OB_X);
    u16* fb    = (u16*)(base + OB_FB);
    u16* PrU   = (u16*)(base + OB_PRU);
    u16* h     = (u16*)(base + OB_H);
    u16* Uh    = (u16*)(base + OB_UH);
    u16* nei   = (u16*)(base + OB_UH);   // overlay after depth loop
    u16* sumh  = (u16*)(base + OB_SH);
    u16* sumgh = (u16*)(base + OB_SGH);
    u16* BzT   = (u16*)(base + OB_BZ);
    u16* BhT   = (u16*)(base + OB_BH);
    u16* BuT   = (u16*)(base + OB_BU);
    u16* BrT   = (u16*)(base + OB_BR);
    u16* BoT   = (u16*)(base + OB_BO);
    float* out = (float*)d_out;

    hipLaunchKernelGGL(k_repack, dim3(384), dim3(256), 0, stream,
                       Wz, Wr, Ur, Wh, Wo, BzT, BhT, BuT, BrT, BoT);
    hipLaunchKernelGGL(k_build_x, dim3(20000), dim3(256), 0, stream, fnode, fmess, x);
    hipLaunchKernelGGL(k_build_fb, dim3(10000), dim3(256), 0, stream, fnode, fb);
    hipLaunchKernelGGL(k_mg_p, dim3(1252), dim3(256), 0, stream, x, BrT, urb, PrU);
    hipLaunchKernelGGL(k_d1,   dim3(1252), dim3(256), 0, stream, x, BzT, BhT, bz, bh, h);
    for (int d = 1; d < 4; ++d) {
        hipLaunchKernelGGL(k_mg_uh, dim3(1252), dim3(256), 0, stream, h, BuT, Uh);
        hipLaunchKernelGGL(k_gather_edge, dim3(5000), dim3(256), 0, stream,
                           h, Uh, PrU, bgraph, sumh, sumgh);
        hipLaunchKernelGGL(k_mg_fused, dim3(1252), dim3(256), 0, stream,
                           x, sumh, sumgh, BzT, BhT, bz, bh, h);
    }
    hipLaunchKernelGGL(k_gather_node, dim3(2500), dim3(256), 0, stream, h, agraph, nei);
    hipLaunchKernelGGL(k_mg_out, dim3(628), dim3(256), 0, stream, fb, nei, BoT, bo, out);
}

// Round 10
// 470.362 us; speedup vs baseline: 1.6603x; 1.2968x over previous
//
#include <hip/hip_runtime.h>
#include <cstddef>
#include <cstdint>

typedef unsigned short u16;
typedef unsigned int   u32;
typedef __bf16  bf16x8 __attribute__((ext_vector_type(8)));
typedef float   f32x4  __attribute__((ext_vector_type(4)));

#define DEV __device__ __forceinline__

DEV float b2f(u16 u) { union { u32 i; float f; } c; c.i = ((u32)u) << 16; return c.f; }
DEV u16 f2b(float x) { union { float f; u32 i; } c; c.f = x; u32 b = c.i;
                       return (u16)((b + 0x7FFFu + ((b >> 16) & 1u)) >> 16); }
DEV float sigm(float x)  { return 1.0f / (1.0f + __expf(-x)); }
DEV float tanh_(float x) { return 1.0f - 2.0f / (1.0f + __expf(2.0f * x)); }
DEV float gelu_(float x) { return 0.5f * x * (1.0f + erff(x * 0.70710678118654752f)); }

DEV void u4tof8(uint4 v, float* f) {
    f[0] = b2f((u16)(v.x & 0xFFFF)); f[1] = b2f((u16)(v.x >> 16));
    f[2] = b2f((u16)(v.y & 0xFFFF)); f[3] = b2f((u16)(v.y >> 16));
    f[4] = b2f((u16)(v.z & 0xFFFF)); f[5] = b2f((u16)(v.z >> 16));
    f[6] = b2f((u16)(v.w & 0xFFFF)); f[7] = b2f((u16)(v.w >> 16));
}
DEV uint4 f8tou4(const float* f) {
    uint4 v;
    v.x = (u32)f2b(f[0]) | ((u32)f2b(f[1]) << 16);
    v.y = (u32)f2b(f[2]) | ((u32)f2b(f[3]) << 16);
    v.z = (u32)f2b(f[4]) | ((u32)f2b(f[5]) << 16);
    v.w = (u32)f2b(f[6]) | ((u32)f2b(f[7]) << 16);
    return v;
}

// ---- workspace byte offsets; total 118,546,432 B (fits: 144,113,664 proven) ----
#define OB_X     0ull            // x  [40000][128] bf16
#define OB_FB    10240000ull     // fb [20000][128] bf16
#define OB_PRU   15360000ull     // PrU [40000][256] bf16 (= x@Wr^T + urb)
#define OB_H     35840000ull     // h   [40000][256] bf16
#define OB_UH    56320000ull     // Uh [40000][256] bf16 ; z overlays (Uh dead after
                                 // gather_edge); nei overlays after depth loop
#define OB_SH    76800000ull     // sumh  [40000][256] bf16
#define OB_SGH   97280000ull     // sumgh [40000][256] bf16
#define OB_BZ    117760000ull    // BzT [256][384] bf16 : Wz[:, :111]|pad|Wz[:,111:]
#define OB_BH    117956608ull    // BhT [256][384] bf16
#define OB_BU    118153216ull    // BuT [256][256] bf16
#define OB_BR    118284288ull    // BrT [256][128] bf16 (Wr, K-pad)
#define OB_BO    118349824ull    // BoT [256][384] bf16 : Wo[:, :98]|pad|Wo[:,98:]
#define WS_BYTES 118546432ull

// REGISTER-BUDGET LAW (measured R3-R9): this toolchain pins MFMA-kernel VGPR
// allocation at ~85 regardless of LDS size, launch_bounds min-waves, or
// amdgpu_waves_per_eu. Kernels whose live demand exceeds it (dual-accumulator
// fused/d1: ~112) spill 190-340MB to scratch. Fix: SPLIT dual-acc kernels into
// two single-acc passes (~75 live) that fit under the cap.

// ---------------------------------------------------------------------------
// Weight repack -> [N][K] bf16. Grid 384x256.
__global__ __launch_bounds__(256) void k_repack(
    const float* __restrict__ Wz, const float* __restrict__ Wr,
    const float* __restrict__ Ur, const float* __restrict__ Wh,
    const float* __restrict__ Wo,
    u16* __restrict__ BzT, u16* __restrict__ BhT, u16* __restrict__ BuT,
    u16* __restrict__ BrT, u16* __restrict__ BoT) {
    int idx = blockIdx.x * 256 + threadIdx.x;   // 0..98303
    {
        int n = idx / 384, k = idx % 384;
        float vz, vh, vo;
        if (k < 111)      { vz = Wz[n * 367 + k];      vh = Wh[n * 367 + k]; }
        else if (k < 128) { vz = 0.0f;                 vh = 0.0f; }
        else              { vz = Wz[n * 367 + k - 17]; vh = Wh[n * 367 + k - 17]; }
        if (k < 98)       vo = Wo[n * 354 + k];
        else if (k < 128) vo = 0.0f;
        else              vo = Wo[n * 354 + k - 30];
        BzT[idx] = f2b(vz); BhT[idx] = f2b(vh); BoT[idx] = f2b(vo);
    }
    if (idx < 65536) BuT[idx] = f2b(Ur[idx]);
    if (idx < 32768) {
        int n = idx >> 7, k = idx & 127;
        BrT[idx] = f2b(k < 111 ? Wr[n * 111 + k] : 0.0f);
    }
}

// x[e][c] (bf16, [40000][128], zero pad). Grid 20000x256 (2 edges/block).
__global__ __launch_bounds__(256) void k_build_x(const float* __restrict__ fnode,
                                                 const float* __restrict__ fmess,
                                                 u16* __restrict__ x) {
    int e = (blockIdx.x << 1) + (threadIdx.x >> 7);
    int c = threadIdx.x & 127;
    int src = (int)fmess[(size_t)e * 15];
    float v = 0.0f;
    if (c < 98)       v = fnode[(size_t)src * 98 + c];
    else if (c < 111) v = fmess[(size_t)e * 15 + 2 + (c - 98)];
    x[(size_t)e * 128 + c] = f2b(v);
}

// fb [20000][128] bf16 zero-padded. Grid 10000x256.
__global__ __launch_bounds__(256) void k_build_fb(const float* __restrict__ fnode,
                                                  u16* __restrict__ fb) {
    int idx = blockIdx.x * 256 + threadIdx.x;
    int n = idx >> 7, c = idx & 127;
    fb[idx] = f2b(c < 98 ? fnode[(size_t)n * 98 + c] : 0.0f);
}

// ---------------------------------------------------------------------------
// Template: BM=128, BN=64, BK=64. 256 threads = 4 waves (2M x 2N),
// wave tile 64x32, acc[4][2]. LDS swizzle: byte ^= (row&7)<<4.
DEV void ldA(const u16* __restrict__ g, size_t row0, int ld, int k0, int tid, uint4* v) {
    #pragma unroll
    for (int it = 0; it < 4; ++it) {
        int r = it * 32 + (tid >> 3);
        int c = (tid & 7) << 3;
        v[it] = *(const uint4*)(g + (row0 + (size_t)r) * ld + k0 + c);
    }
}
DEV void ldB(const u16* __restrict__ g, size_t row0, int ld, int k0, int tid, uint4* v) {
    #pragma unroll
    for (int it = 0; it < 2; ++it) {
        int r = it * 32 + (tid >> 3);
        int c = (tid & 7) << 3;
        v[it] = *(const uint4*)(g + (row0 + (size_t)r) * ld + k0 + c);
    }
}
DEV void wrA(u16* s, int tid, const uint4* v) {
    #pragma unroll
    for (int it = 0; it < 4; ++it) {
        int r = it * 32 + (tid >> 3);
        int c = (tid & 7) << 3;
        int byte = (((r << 6) + c) << 1) ^ ((r & 7) << 4);
        *(uint4*)((char*)s + byte) = v[it];
    }
}
DEV void wrB(u16* s, int tid, const uint4* v) {
    #pragma unroll
    for (int it = 0; it < 2; ++it) {
        int r = it * 32 + (tid >> 3);
        int c = (tid & 7) << 3;
        int byte = (((r << 6) + c) << 1) ^ ((r & 7) << 4);
        *(uint4*)((char*)s + byte) = v[it];
    }
}
// Swapped-operand MFMA: acc[i][j][q] = C[row_l+16i][col_l+16j+q]
DEV void mma_step(const u16* As, const u16* Bs, f32x4 acc[4][2], int lane, int wr, int wc) {
    int rb = (wr << 6) + (lane & 15);
    int cb = (wc << 5) + (lane & 15);
    int ko = (lane >> 4) << 3;
    #pragma unroll
    for (int kh = 0; kh < 2; ++kh) {
        bf16x8 a[4], b[2];
        #pragma unroll
        for (int i = 0; i < 4; ++i) {
            int ar = rb + (i << 4);
            a[i] = *(const bf16x8*)((const char*)As +
                   ((((ar << 6) + (kh << 5) + ko) << 1) ^ ((ar & 7) << 4)));
        }
        #pragma unroll
        for (int j = 0; j < 2; ++j) {
            int br = cb + (j << 4);
            b[j] = *(const bf16x8*)((const char*)Bs +
                   ((((br << 6) + (kh << 5) + ko) << 1) ^ ((br & 7) << 4)));
        }
        #pragma unroll
        for (int i = 0; i < 4; ++i)
            #pragma unroll
            for (int j = 0; j < 2; ++j)
                acc[i][j] = __builtin_amdgcn_mfma_f32_16x16x32_bf16(b[j], a[i], acc[i][j], 0, 0, 0);
    }
}

#define GT_PROLOG()                                            \
    int tid = threadIdx.x, lane = tid & 63, w = tid >> 6;      \
    int wr = w >> 1, wc = w & 1;                               \
    int bm = blockIdx.x >> 2, bn = blockIdx.x & 3;             \
    size_t m0 = (size_t)bm << 7; size_t n0 = (size_t)(bn << 6);\
    int row_l = (wr << 6) + (lane & 15);                       \
    int col_l = (wc << 5) + ((lane >> 4) << 2);

#define ACC_INIT(A)                                            \
    { f32x4 zz = {0.f, 0.f, 0.f, 0.f};                         \
      _Pragma("unroll") for (int i = 0; i < 4; ++i)            \
      _Pragma("unroll") for (int j = 0; j < 2; ++j) A[i][j] = zz; }

// Double-buffered step: mma on cur buffer, write prefetched regs to next buffer,
// one barrier. (wr(next) overlaps mma(cur); barrier protects next mma.)
#define DB_STEP(CUR_A, CUR_B, NXT_A, NXT_B, LD_NEXT2)          \
    mma_step(CUR_A, CUR_B, acc, lane, wr, wc);                 \
    wrA(NXT_A, tid, ra); wrB(NXT_B, tid, rb);                  \
    __syncthreads();                                           \
    LD_NEXT2;

// ---------------------------------------------------------------------------
// k_mg_z: z = sigm([x|sumh] @ BzT^T + bz) -> bf16 zb. K=384, 6 dbuf steps.
// Grid 1252, 24KB LDS, single acc -> ~75 VGPR live, fits under the ~85 cap.
__global__ __launch_bounds__(256) void k_mg_z(
    const u16* __restrict__ x, const u16* __restrict__ sumh,
    const u16* __restrict__ BzT, const float* __restrict__ bz,
    u16* __restrict__ zb) {
    __shared__ u16 As0[8192], As1[8192], Bs0[4096], Bs1[4096];
    GT_PROLOG()
    f32x4 acc[4][2]; ACC_INIT(acc)
    uint4 ra[4], rb[2];
    ldA(x, m0, 128, 0, tid, ra); ldB(BzT, n0, 384, 0, tid, rb);
    wrA(As0, tid, ra); wrB(Bs0, tid, rb);
    __syncthreads();
    ldA(x, m0, 128, 64, tid, ra); ldB(BzT, n0, 384, 64, tid, rb);
    DB_STEP(As0, Bs0, As1, Bs1, (ldA(sumh, m0, 256, 0, tid, ra),   ldB(BzT, n0, 384, 128, tid, rb)))
    DB_STEP(As1, Bs1, As0, Bs0, (ldA(sumh, m0, 256, 64, tid, ra),  ldB(BzT, n0, 384, 192, tid, rb)))
    DB_STEP(As0, Bs0, As1, Bs1, (ldA(sumh, m0, 256, 128, tid, ra), ldB(BzT, n0, 384, 256, tid, rb)))
    DB_STEP(As1, Bs1, As0, Bs0, (ldA(sumh, m0, 256, 192, tid, ra), ldB(BzT, n0, 384, 320, tid, rb)))
    DB_STEP(As0, Bs0, As1, Bs1, ;)
    mma_step(As1, Bs1, acc, lane, wr, wc);
    #pragma unroll
    for (int mi = 0; mi < 4; ++mi) {
        int m = (int)m0 + row_l + (mi << 4);
        if (m >= 40000) continue;
        #pragma unroll
        for (int ni = 0; ni < 2; ++ni) {
            int col = (int)n0 + col_l + (ni << 4);
            float4 vz = *(const float4*)(bz + col);
            ushort4 o;
            o.x = f2b(sigm(acc[mi][ni][0] + vz.x));
            o.y = f2b(sigm(acc[mi][ni][1] + vz.y));
            o.z = f2b(sigm(acc[mi][ni][2] + vz.z));
            o.w = f2b(sigm(acc[mi][ni][3] + vz.w));
            *(ushort4*)(zb + (size_t)m * 256 + col) = o;
        }
    }
}

// k_mg_h: pre = tanh([x|sumgh] @ BhT^T + bh); h = ((1-z)*sumh + z*pre)*emask.
// K=384, 6 dbuf steps. Grid 1252, 24KB LDS, single acc.
__global__ __launch_bounds__(256) void k_mg_h(
    const u16* __restrict__ x, const u16* __restrict__ sumgh,
    const u16* __restrict__ sumh, const u16* __restrict__ zb,
    const u16* __restrict__ BhT, const float* __restrict__ bh,
    u16* __restrict__ h) {
    __shared__ u16 As0[8192], As1[8192], Bs0[4096], Bs1[4096];
    GT_PROLOG()
    f32x4 acc[4][2]; ACC_INIT(acc)
    uint4 ra[4], rb[2];
    ldA(x, m0, 128, 0, tid, ra); ldB(BhT, n0, 384, 0, tid, rb);
    wrA(As0, tid, ra); wrB(Bs0, tid, rb);
    __syncthreads();
    ldA(x, m0, 128, 64, tid, ra); ldB(BhT, n0, 384, 64, tid, rb);
    DB_STEP(As0, Bs0, As1, Bs1, (ldA(sumgh, m0, 256, 0, tid, ra),   ldB(BhT, n0, 384, 128, tid, rb)))
    DB_STEP(As1, Bs1, As0, Bs0, (ldA(sumgh, m0, 256, 64, tid, ra),  ldB(BhT, n0, 384, 192, tid, rb)))
    DB_STEP(As0, Bs0, As1, Bs1, (ldA(sumgh, m0, 256, 128, tid, ra), ldB(BhT, n0, 384, 256, tid, rb)))
    DB_STEP(As1, Bs1, As0, Bs0, (ldA(sumgh, m0, 256, 192, tid, ra), ldB(BhT, n0, 384, 320, tid, rb)))
    DB_STEP(As0, Bs0, As1, Bs1, ;)
    mma_step(As1, Bs1, acc, lane, wr, wc);
    #pragma unroll
    for (int mi = 0; mi < 4; ++mi) {
        int m = (int)m0 + row_l + (mi << 4);
        if (m >= 40000) continue;
        #pragma unroll
        for (int ni = 0; ni < 2; ++ni) {
            int col = (int)n0 + col_l + (ni << 4);
            float4 vh = *(const float4*)(bh + col);
            ushort4 z4  = *(const ushort4*)(zb   + (size_t)m * 256 + col);
            ushort4 sh4 = *(const ushort4*)(sumh + (size_t)m * 256 + col);
            float zv[4]  = {b2f(z4.x),  b2f(z4.y),  b2f(z4.z),  b2f(z4.w)};
            float shv[4] = {b2f(sh4.x), b2f(sh4.y), b2f(sh4.z), b2f(sh4.w)};
            float bhv[4] = {vh.x, vh.y, vh.z, vh.w};
            float o[4];
            #pragma unroll
            for (int q = 0; q < 4; ++q) {
                float pre = tanh_(acc[mi][ni][q] + bhv[q]);
                o[q] = (1.0f - zv[q]) * shv[q] + zv[q] * pre;
            }
            if (m == 0) { o[0] = o[1] = o[2] = o[3] = 0.0f; }
            ushort4 ov;
            ov.x = f2b(o[0]); ov.y = f2b(o[1]); ov.z = f2b(o[2]); ov.w = f2b(o[3]);
            *(ushort4*)(h + (size_t)m * 256 + col) = ov;
        }
    }
}

// k_d1z: z = sigm(x @ Bz_x + bz). K=128, 2 dbuf steps. Grid 1252, 24KB.
__global__ __launch_bounds__(256) void k_d1z(
    const u16* __restrict__ x, const u16* __restrict__ BzT,
    const float* __restrict__ bz, u16* __restrict__ zb) {
    __shared__ u16 As0[8192], As1[8192], Bs0[4096], Bs1[4096];
    GT_PROLOG()
    f32x4 acc[4][2]; ACC_INIT(acc)
    uint4 ra[4], rb[2];
    ldA(x, m0, 128, 0, tid, ra); ldB(BzT, n0, 384, 0, tid, rb);
    wrA(As0, tid, ra); wrB(Bs0, tid, rb);
    __syncthreads();
    ldA(x, m0, 128, 64, tid, ra); ldB(BzT, n0, 384, 64, tid, rb);
    DB_STEP(As0, Bs0, As1, Bs1, ;)
    mma_step(As1, Bs1, acc, lane, wr, wc);
    #pragma unroll
    for (int mi = 0; mi < 4; ++mi) {
        int m = (int)m0 + row_l + (mi << 4);
        if (m >= 40000) continue;
        #pragma unroll
        for (int ni = 0; ni < 2; ++ni) {
            int col = (int)n0 + col_l + (ni << 4);
            float4 vz = *(const float4*)(bz + col);
            ushort4 o;
            o.x = f2b(sigm(acc[mi][ni][0] + vz.x));
            o.y = f2b(sigm(acc[mi][ni][1] + vz.y));
            o.z = f2b(sigm(acc[mi][ni][2] + vz.z));
            o.w = f2b(sigm(acc[mi][ni][3] + vz.w));
            *(ushort4*)(zb + (size_t)m * 256 + col) = o;
        }
    }
}

// k_d1h: h = z * tanh(x @ Bh_x + bh), row0 masked. K=128. Grid 1252, 24KB.
__global__ __launch_bounds__(256) void k_d1h(
    const u16* __restrict__ x, const u16* __restrict__ zb,
    const u16* __restrict__ BhT, const float* __restrict__ bh,
    u16* __restrict__ h) {
    __shared__ u16 As0[8192], As1[8192], Bs0[4096], Bs1[4096];
    GT_PROLOG()
    f32x4 acc[4][2]; ACC_INIT(acc)
    uint4 ra[4], rb[2];
    ldA(x, m0, 128, 0, tid, ra); ldB(BhT, n0, 384, 0, tid, rb);
    wrA(As0, tid, ra); wrB(Bs0, tid, rb);
    __syncthreads();
    ldA(x, m0, 128, 64, tid, ra); ldB(BhT, n0, 384, 64, tid, rb);
    DB_STEP(As0, Bs0, As1, Bs1, ;)
    mma_step(As1, Bs1, acc, lane, wr, wc);
    #pragma unroll
    for (int mi = 0; mi < 4; ++mi) {
        int m = (int)m0 + row_l + (mi << 4);
        if (m >= 40000) continue;
        #pragma unroll
        for (int ni = 0; ni < 2; ++ni) {
            int col = (int)n0 + col_l + (ni << 4);
            float4 vh = *(const float4*)(bh + col);
            ushort4 z4 = *(const ushort4*)(zb + (size_t)m * 256 + col);
            float zv[4] = {b2f(z4.x), b2f(z4.y), b2f(z4.z), b2f(z4.w)};
            float o[4];
            o[0] = zv[0] * tanh_(acc[mi][ni][0] + vh.x);
            o[1] = zv[1] * tanh_(acc[mi][ni][1] + vh.y);
            o[2] = zv[2] * tanh_(acc[mi][ni][2] + vh.z);
            o[3] = zv[3] * tanh_(acc[mi][ni][3] + vh.w);
            if (m == 0) { o[0] = o[1] = o[2] = o[3] = 0.0f; }
            ushort4 ov;
            ov.x = f2b(o[0]); ov.y = f2b(o[1]); ov.z = f2b(o[2]); ov.w = f2b(o[3]);
            *(ushort4*)(h + (size_t)m * 256 + col) = ov;
        }
    }
}

// Uh = h @ BuT^T. K=256, 4 dbuf steps. Grid 1252. 48KB (no spill, proven R8/R9).
__global__ __launch_bounds__(256) void k_mg_uh(
    const u16* __restrict__ A, const u16* __restrict__ BT, u16* __restrict__ C) {
    __shared__ u16 As0[8192], As1[8192], Bs0[4096], Bs1[4096];
    GT_PROLOG()
    f32x4 acc[4][2]; ACC_INIT(acc)
    uint4 ra[4], rb[2];
    ldA(A, m0, 256, 0, tid, ra); ldB(BT, n0, 256, 0, tid, rb);
    wrA(As0, tid, ra); wrB(Bs0, tid, rb);
    __syncthreads();
    ldA(A, m0, 256, 64, tid, ra); ldB(BT, n0, 256, 64, tid, rb);
    DB_STEP(As0, Bs0, As1, Bs1, (ldA(A, m0, 256, 128, tid, ra), ldB(BT, n0, 256, 128, tid, rb)))
    DB_STEP(As1, Bs1, As0, Bs0, (ldA(A, m0, 256, 192, tid, ra), ldB(BT, n0, 256, 192, tid, rb)))
    DB_STEP(As0, Bs0, As1, Bs1, ;)
    mma_step(As1, Bs1, acc, lane, wr, wc);
    #pragma unroll
    for (int mi = 0; mi < 4; ++mi) {
        int m = (int)m0 + row_l + (mi << 4);
        if (m >= 40000) continue;
        #pragma unroll
        for (int ni = 0; ni < 2; ++ni) {
            int col = (int)n0 + col_l + (ni << 4);
            ushort4 o;
            o.x = f2b(acc[mi][ni][0]); o.y = f2b(acc[mi][ni][1]);
            o.z = f2b(acc[mi][ni][2]); o.w = f2b(acc[mi][ni][3]);
            *(ushort4*)(C + (size_t)m * 256 + col) = o;
        }
    }
}

// PrU = x @ BrT^T + urb. K=128, 2 dbuf steps. Grid 1252. 24KB.
__global__ __launch_bounds__(256) void k_mg_p(
    const u16* __restrict__ x, const u16* __restrict__ BrT,
    const float* __restrict__ urb, u16* __restrict__ PrU) {
    __shared__ u16 As0[8192], As1[8192], Bs0[4096], Bs1[4096];
    GT_PROLOG()
    f32x4 acc[4][2]; ACC_INIT(acc)
    uint4 ra[4], rb[2];
    ldA(x, m0, 128, 0, tid, ra); ldB(BrT, n0, 128, 0, tid, rb);
    wrA(As0, tid, ra); wrB(Bs0, tid, rb);
    __syncthreads();
    ldA(x, m0, 128, 64, tid, ra); ldB(BrT, n0, 128, 64, tid, rb);
    DB_STEP(As0, Bs0, As1, Bs1, ;)
    mma_step(As1, Bs1, acc, lane, wr, wc);
    #pragma unroll
    for (int mi = 0; mi < 4; ++mi) {
        int m = (int)m0 + row_l + (mi << 4);
        if (m >= 40000) continue;
        #pragma unroll
        for (int ni = 0; ni < 2; ++ni) {
            int col = (int)n0 + col_l + (ni << 4);
            float4 ub = *(const float4*)(urb + col);
            ushort4 o;
            o.x = f2b(acc[mi][ni][0] + ub.x); o.y = f2b(acc[mi][ni][1] + ub.y);
            o.z = f2b(acc[mi][ni][2] + ub.z); o.w = f2b(acc[mi][ni][3] + ub.w);
            *(ushort4*)(PrU + (size_t)m * 256 + col) = o;
        }
    }
}

// out = gelu([fb|nei]@Bo + bo). K=384, 6 dbuf steps. Grid 628. 48KB. f32, row0 masked.
__global__ __launch_bounds__(256) void k_mg_out(
    const u16* __restrict__ fb, const u16* __restrict__ nei,
    const u16* __restrict__ BoT, const float* __restrict__ bo,
    float* __restrict__ out) {
    __shared__ u16 As0[8192], As1[8192], Bs0[4096], Bs1[4096];
    GT_PROLOG()
    f32x4 acc[4][2]; ACC_INIT(acc)
    uint4 ra[4], rb[2];
    ldA(fb, m0, 128, 0, tid, ra); ldB(BoT, n0, 384, 0, tid, rb);
    wrA(As0, tid, ra); wrB(Bs0, tid, rb);
    __syncthreads();
    ldA(fb, m0, 128, 64, tid, ra); ldB(BoT, n0, 384, 64, tid, rb);
    DB_STEP(As0, Bs0, As1, Bs1, (ldA(nei, m0, 256, 0, tid, ra),   ldB(BoT, n0, 384, 128, tid, rb)))
    DB_STEP(As1, Bs1, As0, Bs0, (ldA(nei, m0, 256, 64, tid, ra),  ldB(BoT, n0, 384, 192, tid, rb)))
    DB_STEP(As0, Bs0, As1, Bs1, (ldA(nei, m0, 256, 128, tid, ra), ldB(BoT, n0, 384, 256, tid, rb)))
    DB_STEP(As1, Bs1, As0, Bs0, (ldA(nei, m0, 256, 192, tid, ra), ldB(BoT, n0, 384, 320, tid, rb)))
    DB_STEP(As0, Bs0, As1, Bs1, ;)
    mma_step(As1, Bs1, acc, lane, wr, wc);
    #pragma unroll
    for (int mi = 0; mi < 4; ++mi) {
        int m = (int)m0 + row_l + (mi << 4);
        if (m >= 20000) continue;
        #pragma unroll
        for (int ni = 0; ni < 2; ++ni) {
            int col = (int)n0 + col_l + (ni << 4);
            float4 vb = *(const float4*)(bo + col);
            float4 o;
            o.x = gelu_(acc[mi][ni][0] + vb.x);
            o.y = gelu_(acc[mi][ni][1] + vb.y);
            o.z = gelu_(acc[mi][ni][2] + vb.z);
            o.w = gelu_(acc[mi][ni][3] + vb.w);
            if (m == 0) { o.x = o.y = o.z = o.w = 0.0f; }
            *(float4*)(out + (size_t)m * 256 + col) = o;
        }
    }
}

// ---------------------------------------------------------------------------
// sumh/sumgh gather. Grid 5000x256.
__global__ __launch_bounds__(256) void k_gather_edge(
    const u16* __restrict__ h, const u16* __restrict__ Uh,
    const u16* __restrict__ PrU, const int* __restrict__ bgraph,
    u16* __restrict__ sumh, u16* __restrict__ sumgh) {
    int e = (blockIdx.x << 3) + (threadIdx.x >> 5);
    int c = (threadIdx.x & 31) << 3;
    size_t o = (size_t)e * 256 + c;
    float pr[8];
    u4tof8(*(const uint4*)(PrU + o), pr);
    float sh[8] = {}, sg[8] = {};
    #pragma unroll
    for (int j = 0; j < 6; ++j) {
        int b = bgraph[e * 6 + j];
        float hv[8], uv[8];
        u4tof8(*(const uint4*)(h  + (size_t)b * 256 + c), hv);
        u4tof8(*(const uint4*)(Uh + (size_t)b * 256 + c), uv);
        #pragma unroll
        for (int q = 0; q < 8; ++q) {
            sh[q] += hv[q];
            sg[q] += sigm(pr[q] + uv[q]) * hv[q];
        }
    }
    *(uint4*)(sumh  + o) = f8tou4(sh);
    *(uint4*)(sumgh + o) = f8tou4(sg);
}

// nei[n] = bf16(sum_j h[agraph[n][j]]). Grid 2500x256.
__global__ __launch_bounds__(256) void k_gather_node(
    const u16* __restrict__ h, const int* __restrict__ agraph,
    u16* __restrict__ nei) {
    int n = (blockIdx.x << 3) + (threadIdx.x >> 5);
    int c = (threadIdx.x & 31) << 3;
    float s[8] = {};
    #pragma unroll
    for (int j = 0; j < 6; ++j) {
        int a = agraph[n * 6 + j];
        float hv[8];
        u4tof8(*(const uint4*)(h + (size_t)a * 256 + c), hv);
        #pragma unroll
        for (int q = 0; q < 8; ++q) s[q] += hv[q];
    }
    *(uint4*)(nei + (size_t)n * 256 + c) = f8tou4(s);
}

// ---------------------------------------------------------------------------
extern "C" void kernel_launch(void* const* d_in, const int* in_sizes, int n_in,
                              void* d_out, int out_size, void* d_ws, size_t ws_size,
                              hipStream_t stream) {
    if (ws_size < WS_BYTES) return;

    const float* fnode  = (const float*)d_in[0];
    const float* fmess  = (const float*)d_in[1];
    const int*   agraph = (const int*)d_in[2];
    const int*   bgraph = (const int*)d_in[3];
    const float* Wz  = (const float*)d_in[4];
    const float* bz  = (const float*)d_in[5];
    const float* Wr  = (const float*)d_in[6];
    const float* Ur  = (const float*)d_in[7];
    const float* urb = (const float*)d_in[8];
    const float* Wh  = (const float*)d_in[9];
    const float* bh  = (const float*)d_in[10];
    const float* Wo  = (const float*)d_in[11];
    const float* bo  = (const float*)d_in[12];

    char* base = (char*)d_ws;
    u16* x     = (u16*)(base + OB_X);
    u16* fb    = (u16*)(base + OB_FB);
    u16* PrU   = (u16*)(base + OB_PRU);
    u16* h     = (u16*)(base + OB_H);
    u16* Uh    = (u16*)(base + OB_UH);
    u16* zb    = (u16*)(base + OB_UH);   // overlay: Uh dead after gather_edge
    u16* nei   = (u16*)(base + OB_UH);   // overlay: after depth loop
    u16* sumh  = (u16*)(base + OB_SH);
    u16* sumgh = (u16*)(base + OB_SGH);
    u16* BzT   = (u16*)(base + OB_BZ);
    u16* BhT   = (u16*)(base + OB_BH);
    u16* BuT   = (u16*)(base + OB_BU);
    u16* BrT   = (u16*)(base + OB_BR);
    u16* BoT   = (u16*)(base + OB_BO);
    float* out = (float*)d_out;

    hipLaunchKernelGGL(k_repack, dim3(384), dim3(256), 0, stream,
                       Wz, Wr, Ur, Wh, Wo, BzT, BhT, BuT, BrT, BoT);
    hipLaunchKernelGGL(k_build_x, dim3(20000), dim3(256), 0, stream, fnode, fmess, x);
    hipLaunchKernelGGL(k_build_fb, dim3(10000), dim3(256), 0, stream, fnode, fb);
    hipLaunchKernelGGL(k_mg_p, dim3(1252), dim3(256), 0, stream, x, BrT, urb, PrU);
    hipLaunchKernelGGL(k_d1z, dim3(1252), dim3(256), 0, stream, x, BzT, bz, zb);
    hipLaunchKernelGGL(k_d1h, dim3(1252), dim3(256), 0, stream, x, zb, BhT, bh, h);
    for (int d = 1; d < 4; ++d) {
        hipLaunchKernelGGL(k_mg_uh, dim3(1252), dim3(256), 0, stream, h, BuT, Uh);
        hipLaunchKernelGGL(k_gather_edge, dim3(5000), dim3(256), 0, stream,
                           h, Uh, PrU, bgraph, sumh, sumgh);
        hipLaunchKernelGGL(k_mg_z, dim3(1252), dim3(256), 0, stream,
                           x, sumh, BzT, bz, zb);
        hipLaunchKernelGGL(k_mg_h, dim3(1252), dim3(256), 0, stream,
                           x, sumgh, sumh, zb, BhT, bh, h);
    }
    hipLaunchKernelGGL(k_gather_node, dim3(2500), dim3(256), 0, stream, h, agraph, nei);
    hipLaunchKernelGGL(k_mg_out, dim3(628), dim3(256), 0, stream, fb, nei, BoT, bo, out);
}

// Round 11
// 444.102 us; speedup vs baseline: 1.7585x; 1.0591x over previous
//
#include <hip/hip_runtime.h>
#include <cstddef>
#include <cstdint>

typedef unsigned short u16;
typedef unsigned int   u32;
typedef __bf16  bf16x8 __attribute__((ext_vector_type(8)));
typedef float   f32x4  __attribute__((ext_vector_type(4)));

#define DEV __device__ __forceinline__

DEV float b2f(u16 u) { union { u32 i; float f; } c; c.i = ((u32)u) << 16; return c.f; }
DEV u16 f2b(float x) { union { float f; u32 i; } c; c.f = x; u32 b = c.i;
                       return (u16)((b + 0x7FFFu + ((b >> 16) & 1u)) >> 16); }
DEV float sigm(float x)  { return 1.0f / (1.0f + __expf(-x)); }
DEV float tanh_(float x) { return 1.0f - 2.0f / (1.0f + __expf(2.0f * x)); }
DEV float gelu_(float x) { return 0.5f * x * (1.0f + erff(x * 0.70710678118654752f)); }

DEV void u4tof8(uint4 v, float* f) {
    f[0] = b2f((u16)(v.x & 0xFFFF)); f[1] = b2f((u16)(v.x >> 16));
    f[2] = b2f((u16)(v.y & 0xFFFF)); f[3] = b2f((u16)(v.y >> 16));
    f[4] = b2f((u16)(v.z & 0xFFFF)); f[5] = b2f((u16)(v.z >> 16));
    f[6] = b2f((u16)(v.w & 0xFFFF)); f[7] = b2f((u16)(v.w >> 16));
}
DEV uint4 f8tou4(const float* f) {
    uint4 v;
    v.x = (u32)f2b(f[0]) | ((u32)f2b(f[1]) << 16);
    v.y = (u32)f2b(f[2]) | ((u32)f2b(f[3]) << 16);
    v.z = (u32)f2b(f[4]) | ((u32)f2b(f[5]) << 16);
    v.w = (u32)f2b(f[6]) | ((u32)f2b(f[7]) << 16);
    return v;
}

// ---- workspace byte offsets; total 144,015,360 B (<=144,113,664 proven) ----
#define OB_PRU   0ull            // PrU [40000][256] bf16 (x@Wr^T + urb)
#define OB_PZX   20480000ull     // Pzx [40000][256] bf16 (x@Wzx^T, depth-invariant)
#define OB_PHX   40960000ull     // Phx [40000][256] bf16
#define OB_H     61440000ull     // h   [40000][256] bf16
#define OB_UH    81920000ull     // Uh [40000][256] bf16; zb/nei overlay; Br/Box overlay in prologue
#define OB_SH    102400000ull    // sumh [40000][256] bf16 ; x [40000][128] overlays in prologue
#define OB_SGH   122880000ull    // sumgh [40000][256] bf16 ; fb [20000][128] overlays in prologue
#define OB_BZX   143360000ull    // [256][128] Wz[:, :111] K-pad
#define OB_BZH   143425536ull    // [256][256] Wz[:, 111:]
#define OB_BHX   143556608ull    // [256][128] Wh[:, :111]
#define OB_BHH   143622144ull    // [256][256] Wh[:, 111:]
#define OB_BU    143753216ull    // [256][256] U_r
#define OB_BOH   143884288ull    // [256][256] Wo[:, 98:]
#define OB_BR    OB_UH           // [256][128] Wr (prologue only; clobbered by Uh)
#define OB_BOX   (OB_UH + 65536ull) // [256][128] Wo[:, :98] (prologue only)
#define WS_BYTES 144015360ull

// REGISTER LAW (R3-R10): MFMA kernels spill catastrophically above ~85 live
// VGPRs on this toolchain (no attribute overrides it). All GEMM kernels here
// are single-accumulator (acc 32 + prefetch 24 + addr ~20 < 85). R10 proved
// this: spill-free, 610->470us.

// XCD-aware bijective swizzle (T1/m204): consecutive HW blocks round-robin
// XCDs; remap so the 4 blocks sharing one A-tile land on ONE XCD's L2.
DEV int xcd_swz(int bid, int nwg) {
    int q = nwg >> 3, r = nwg & 7;
    int xcd = bid & 7, idx = bid >> 3;
    return (xcd < r ? xcd * (q + 1) : r * (q + 1) + (xcd - r) * q) + idx;
}

// ---------------------------------------------------------------------------
// Weight repack -> [N][K] bf16. Grid 256x256.
__global__ __launch_bounds__(256) void k_repack(
    const float* __restrict__ Wz, const float* __restrict__ Wr,
    const float* __restrict__ Ur, const float* __restrict__ Wh,
    const float* __restrict__ Wo,
    u16* __restrict__ BzxT, u16* __restrict__ BzhT, u16* __restrict__ BhxT,
    u16* __restrict__ BhhT, u16* __restrict__ BuT, u16* __restrict__ BohT,
    u16* __restrict__ BrT, u16* __restrict__ BoxT) {
    int idx = blockIdx.x * 256 + threadIdx.x;   // 0..65535
    {
        int n = idx >> 8, k = idx & 255;
        BzhT[idx] = f2b(Wz[n * 367 + 111 + k]);
        BhhT[idx] = f2b(Wh[n * 367 + 111 + k]);
        BuT[idx]  = f2b(Ur[idx]);
        BohT[idx] = f2b(Wo[n * 354 + 98 + k]);
    }
    if (idx < 32768) {
        int n = idx >> 7, k = idx & 127;
        BzxT[idx] = f2b(k < 111 ? Wz[n * 367 + k] : 0.0f);
        BhxT[idx] = f2b(k < 111 ? Wh[n * 367 + k] : 0.0f);
        BrT[idx]  = f2b(k < 111 ? Wr[n * 111 + k] : 0.0f);
        BoxT[idx] = f2b(k < 98  ? Wo[n * 354 + k] : 0.0f);
    }
}

// x[e][c] (bf16, [40000][128], zero pad). Grid 20000x256.
__global__ __launch_bounds__(256) void k_build_x(const float* __restrict__ fnode,
                                                 const float* __restrict__ fmess,
                                                 u16* __restrict__ x) {
    int e = (blockIdx.x << 1) + (threadIdx.x >> 7);
    int c = threadIdx.x & 127;
    int src = (int)fmess[(size_t)e * 15];
    float v = 0.0f;
    if (c < 98)       v = fnode[(size_t)src * 98 + c];
    else if (c < 111) v = fmess[(size_t)e * 15 + 2 + (c - 98)];
    x[(size_t)e * 128 + c] = f2b(v);
}

// fb [20000][128] bf16 zero-padded. Grid 10000x256.
__global__ __launch_bounds__(256) void k_build_fb(const float* __restrict__ fnode,
                                                  u16* __restrict__ fb) {
    int idx = blockIdx.x * 256 + threadIdx.x;
    int n = idx >> 7, c = idx & 127;
    fb[idx] = f2b(c < 98 ? fnode[(size_t)n * 98 + c] : 0.0f);
}

// ---------------------------------------------------------------------------
// Template: BM=128, BN=64, BK=64. 256 threads = 4 waves (2M x 2N),
// wave tile 64x32, acc[4][2]. LDS 24KB dbuf, swizzle byte ^= (row&7)<<4.
DEV void ldA(const u16* __restrict__ g, size_t row0, int ld, int k0, int tid, uint4* v) {
    #pragma unroll
    for (int it = 0; it < 4; ++it) {
        int r = it * 32 + (tid >> 3);
        int c = (tid & 7) << 3;
        v[it] = *(const uint4*)(g + (row0 + (size_t)r) * ld + k0 + c);
    }
}
DEV void ldB(const u16* __restrict__ g, size_t row0, int ld, int k0, int tid, uint4* v) {
    #pragma unroll
    for (int it = 0; it < 2; ++it) {
        int r = it * 32 + (tid >> 3);
        int c = (tid & 7) << 3;
        v[it] = *(const uint4*)(g + (row0 + (size_t)r) * ld + k0 + c);
    }
}
DEV void wrA(u16* s, int tid, const uint4* v) {
    #pragma unroll
    for (int it = 0; it < 4; ++it) {
        int r = it * 32 + (tid >> 3);
        int c = (tid & 7) << 3;
        int byte = (((r << 6) + c) << 1) ^ ((r & 7) << 4);
        *(uint4*)((char*)s + byte) = v[it];
    }
}
DEV void wrB(u16* s, int tid, const uint4* v) {
    #pragma unroll
    for (int it = 0; it < 2; ++it) {
        int r = it * 32 + (tid >> 3);
        int c = (tid & 7) << 3;
        int byte = (((r << 6) + c) << 1) ^ ((r & 7) << 4);
        *(uint4*)((char*)s + byte) = v[it];
    }
}
// Swapped-operand MFMA: acc[i][j][q] = C[row_l+16i][col_l+16j+q]
DEV void mma_step(const u16* As, const u16* Bs, f32x4 acc[4][2], int lane, int wr, int wc) {
    int rb = (wr << 6) + (lane & 15);
    int cb = (wc << 5) + (lane & 15);
    int ko = (lane >> 4) << 3;
    #pragma unroll
    for (int kh = 0; kh < 2; ++kh) {
        bf16x8 a[4], b[2];
        #pragma unroll
        for (int i = 0; i < 4; ++i) {
            int ar = rb + (i << 4);
            a[i] = *(const bf16x8*)((const char*)As +
                   ((((ar << 6) + (kh << 5) + ko) << 1) ^ ((ar & 7) << 4)));
        }
        #pragma unroll
        for (int j = 0; j < 2; ++j) {
            int br = cb + (j << 4);
            b[j] = *(const bf16x8*)((const char*)Bs +
                   ((((br << 6) + (kh << 5) + ko) << 1) ^ ((br & 7) << 4)));
        }
        #pragma unroll
        for (int i = 0; i < 4; ++i)
            #pragma unroll
            for (int j = 0; j < 2; ++j)
                acc[i][j] = __builtin_amdgcn_mfma_f32_16x16x32_bf16(b[j], a[i], acc[i][j], 0, 0, 0);
    }
}

#define GT_PROLOG()                                            \
    int tid = threadIdx.x, lane = tid & 63, w = tid >> 6;      \
    int wr = w >> 1, wc = w & 1;                               \
    int bid = xcd_swz((int)blockIdx.x, (int)gridDim.x);        \
    int bm = bid >> 2, bn = bid & 3;                           \
    size_t m0 = (size_t)bm << 7; size_t n0 = (size_t)(bn << 6);\
    int row_l = (wr << 6) + (lane & 15);                       \
    int col_l = (wc << 5) + ((lane >> 4) << 2);

#define ACC_INIT(A)                                            \
    { f32x4 zz = {0.f, 0.f, 0.f, 0.f};                         \
      _Pragma("unroll") for (int i = 0; i < 4; ++i)            \
      _Pragma("unroll") for (int j = 0; j < 2; ++j) A[i][j] = zz; }

#define DB_STEP(CUR_A, CUR_B, NXT_A, NXT_B, LD_NEXT2)          \
    mma_step(CUR_A, CUR_B, acc, lane, wr, wc);                 \
    wrA(NXT_A, tid, ra); wrB(NXT_B, tid, rb);                  \
    __syncthreads();                                           \
    LD_NEXT2;

// ---------------------------------------------------------------------------
// Generic K=128: out = A@BT^T (+bias). For PrU (bias=urb), Pzx, Phx. Grid 1252.
__global__ __launch_bounds__(256) void k_mg_k128(
    const u16* __restrict__ A, const u16* __restrict__ BT,
    const float* __restrict__ bias, u16* __restrict__ out) {
    __shared__ u16 As0[8192], As1[8192], Bs0[4096], Bs1[4096];
    GT_PROLOG()
    f32x4 acc[4][2]; ACC_INIT(acc)
    uint4 ra[4], rb[2];
    ldA(A, m0, 128, 0, tid, ra); ldB(BT, n0, 128, 0, tid, rb);
    wrA(As0, tid, ra); wrB(Bs0, tid, rb);
    __syncthreads();
    ldA(A, m0, 128, 64, tid, ra); ldB(BT, n0, 128, 64, tid, rb);
    DB_STEP(As0, Bs0, As1, Bs1, ;)
    mma_step(As1, Bs1, acc, lane, wr, wc);
    #pragma unroll
    for (int mi = 0; mi < 4; ++mi) {
        int m = (int)m0 + row_l + (mi << 4);
        if (m >= 40000) continue;
        #pragma unroll
        for (int ni = 0; ni < 2; ++ni) {
            int col = (int)n0 + col_l + (ni << 4);
            float4 ub = bias ? *(const float4*)(bias + col)
                             : make_float4(0.f, 0.f, 0.f, 0.f);
            ushort4 o;
            o.x = f2b(acc[mi][ni][0] + ub.x); o.y = f2b(acc[mi][ni][1] + ub.y);
            o.z = f2b(acc[mi][ni][2] + ub.z); o.w = f2b(acc[mi][ni][3] + ub.w);
            *(ushort4*)(out + (size_t)m * 256 + col) = o;
        }
    }
}

// Pn = fb @ BoxT^T -> f32 d_out. K=128, M=20000. Grid 628.
__global__ __launch_bounds__(256) void k_mg_pn(
    const u16* __restrict__ fb, const u16* __restrict__ BT,
    float* __restrict__ out) {
    __shared__ u16 As0[8192], As1[8192], Bs0[4096], Bs1[4096];
    GT_PROLOG()
    f32x4 acc[4][2]; ACC_INIT(acc)
    uint4 ra[4], rb[2];
    ldA(fb, m0, 128, 0, tid, ra); ldB(BT, n0, 128, 0, tid, rb);
    wrA(As0, tid, ra); wrB(Bs0, tid, rb);
    __syncthreads();
    ldA(fb, m0, 128, 64, tid, ra); ldB(BT, n0, 128, 64, tid, rb);
    DB_STEP(As0, Bs0, As1, Bs1, ;)
    mma_step(As1, Bs1, acc, lane, wr, wc);
    #pragma unroll
    for (int mi = 0; mi < 4; ++mi) {
        int m = (int)m0 + row_l + (mi << 4);
        if (m >= 20000) continue;
        #pragma unroll
        for (int ni = 0; ni < 2; ++ni) {
            int col = (int)n0 + col_l + (ni << 4);
            #pragma unroll
            for (int q = 0; q < 4; ++q)
                out[(size_t)m * 256 + col + q] = acc[mi][ni][q];
        }
    }
}

// Depth-1 elementwise: h = sigm(Pzx+bz)*tanh(Phx+bh), row0 mask. Grid 5000.
__global__ __launch_bounds__(256) void k_d1(
    const u16* __restrict__ Pzx, const u16* __restrict__ Phx,
    const float* __restrict__ bz, const float* __restrict__ bh,
    u16* __restrict__ h) {
    int idx = blockIdx.x * 256 + threadIdx.x;
    int e = idx >> 5, c = (idx & 31) << 3;
    size_t o = (size_t)e * 256 + c;
    float pz[8], ph[8], r[8];
    u4tof8(*(const uint4*)(Pzx + o), pz);
    u4tof8(*(const uint4*)(Phx + o), ph);
    #pragma unroll
    for (int q = 0; q < 8; ++q)
        r[q] = (e == 0) ? 0.0f : sigm(pz[q] + bz[c + q]) * tanh_(ph[q] + bh[c + q]);
    *(uint4*)(h + o) = f8tou4(r);
}

// Uh = h @ BuT^T. K=256, 4 dbuf steps. Grid 1252.
__global__ __launch_bounds__(256) void k_mg_uh(
    const u16* __restrict__ A, const u16* __restrict__ BT, u16* __restrict__ C) {
    __shared__ u16 As0[8192], As1[8192], Bs0[4096], Bs1[4096];
    GT_PROLOG()
    f32x4 acc[4][2]; ACC_INIT(acc)
    uint4 ra[4], rb[2];
    ldA(A, m0, 256, 0, tid, ra); ldB(BT, n0, 256, 0, tid, rb);
    wrA(As0, tid, ra); wrB(Bs0, tid, rb);
    __syncthreads();
    ldA(A, m0, 256, 64, tid, ra); ldB(BT, n0, 256, 64, tid, rb);
    DB_STEP(As0, Bs0, As1, Bs1, (ldA(A, m0, 256, 128, tid, ra), ldB(BT, n0, 256, 128, tid, rb)))
    DB_STEP(As1, Bs1, As0, Bs0, (ldA(A, m0, 256, 192, tid, ra), ldB(BT, n0, 256, 192, tid, rb)))
    DB_STEP(As0, Bs0, As1, Bs1, ;)
    mma_step(As1, Bs1, acc, lane, wr, wc);
    #pragma unroll
    for (int mi = 0; mi < 4; ++mi) {
        int m = (int)m0 + row_l + (mi << 4);
        if (m >= 40000) continue;
        #pragma unroll
        for (int ni = 0; ni < 2; ++ni) {
            int col = (int)n0 + col_l + (ni << 4);
            ushort4 o;
            o.x = f2b(acc[mi][ni][0]); o.y = f2b(acc[mi][ni][1]);
            o.z = f2b(acc[mi][ni][2]); o.w = f2b(acc[mi][ni][3]);
            *(ushort4*)(C + (size_t)m * 256 + col) = o;
        }
    }
}

// z = sigm(sumh@BzhT^T + Pzx + bz) -> zb. K=256. Grid 1252.
__global__ __launch_bounds__(256) void k_mg_z(
    const u16* __restrict__ sumh, const u16* __restrict__ BT,
    const u16* __restrict__ Pzx, const float* __restrict__ bz,
    u16* __restrict__ zb) {
    __shared__ u16 As0[8192], As1[8192], Bs0[4096], Bs1[4096];
    GT_PROLOG()
    f32x4 acc[4][2]; ACC_INIT(acc)
    uint4 ra[4], rb[2];
    ldA(sumh, m0, 256, 0, tid, ra); ldB(BT, n0, 256, 0, tid, rb);
    wrA(As0, tid, ra); wrB(Bs0, tid, rb);
    __syncthreads();
    ldA(sumh, m0, 256, 64, tid, ra); ldB(BT, n0, 256, 64, tid, rb);
    DB_STEP(As0, Bs0, As1, Bs1, (ldA(sumh, m0, 256, 128, tid, ra), ldB(BT, n0, 256, 128, tid, rb)))
    DB_STEP(As1, Bs1, As0, Bs0, (ldA(sumh, m0, 256, 192, tid, ra), ldB(BT, n0, 256, 192, tid, rb)))
    DB_STEP(As0, Bs0, As1, Bs1, ;)
    mma_step(As1, Bs1, acc, lane, wr, wc);
    #pragma unroll
    for (int mi = 0; mi < 4; ++mi) {
        int m = (int)m0 + row_l + (mi << 4);
        if (m >= 40000) continue;
        #pragma unroll
        for (int ni = 0; ni < 2; ++ni) {
            int col = (int)n0 + col_l + (ni << 4);
            float4 vz = *(const float4*)(bz + col);
            ushort4 p4 = *(const ushort4*)(Pzx + (size_t)m * 256 + col);
            ushort4 o;
            o.x = f2b(sigm(acc[mi][ni][0] + b2f(p4.x) + vz.x));
            o.y = f2b(sigm(acc[mi][ni][1] + b2f(p4.y) + vz.y));
            o.z = f2b(sigm(acc[mi][ni][2] + b2f(p4.z) + vz.z));
            o.w = f2b(sigm(acc[mi][ni][3] + b2f(p4.w) + vz.w));
            *(ushort4*)(zb + (size_t)m * 256 + col) = o;
        }
    }
}

// pre = tanh(sumgh@BhhT^T + Phx + bh); h = ((1-z)*sumh + z*pre)*emask. K=256.
__global__ __launch_bounds__(256) void k_mg_h(
    const u16* __restrict__ sumgh, const u16* __restrict__ BT,
    const u16* __restrict__ Phx, const float* __restrict__ bh,
    const u16* __restrict__ zb, const u16* __restrict__ sumh,
    u16* __restrict__ h) {
    __shared__ u16 As0[8192], As1[8192], Bs0[4096], Bs1[4096];
    GT_PROLOG()
    f32x4 acc[4][2]; ACC_INIT(acc)
    uint4 ra[4], rb[2];
    ldA(sumgh, m0, 256, 0, tid, ra); ldB(BT, n0, 256, 0, tid, rb);
    wrA(As0, tid, ra); wrB(Bs0, tid, rb);
    __syncthreads();
    ldA(sumgh, m0, 256, 64, tid, ra); ldB(BT, n0, 256, 64, tid, rb);
    DB_STEP(As0, Bs0, As1, Bs1, (ldA(sumgh, m0, 256, 128, tid, ra), ldB(BT, n0, 256, 128, tid, rb)))
    DB_STEP(As1, Bs1, As0, Bs0, (ldA(sumgh, m0, 256, 192, tid, ra), ldB(BT, n0, 256, 192, tid, rb)))
    DB_STEP(As0, Bs0, As1, Bs1, ;)
    mma_step(As1, Bs1, acc, lane, wr, wc);
    #pragma unroll
    for (int mi = 0; mi < 4; ++mi) {
        int m = (int)m0 + row_l + (mi << 4);
        if (m >= 40000) continue;
        #pragma unroll
        for (int ni = 0; ni < 2; ++ni) {
            int col = (int)n0 + col_l + (ni << 4);
            float4 vh = *(const float4*)(bh + col);
            ushort4 p4  = *(const ushort4*)(Phx  + (size_t)m * 256 + col);
            ushort4 z4  = *(const ushort4*)(zb   + (size_t)m * 256 + col);
            ushort4 sh4 = *(const ushort4*)(sumh + (size_t)m * 256 + col);
            float pv[4]  = {b2f(p4.x),  b2f(p4.y),  b2f(p4.z),  b2f(p4.w)};
            float zv[4]  = {b2f(z4.x),  b2f(z4.y),  b2f(z4.z),  b2f(z4.w)};
            float shv[4] = {b2f(sh4.x), b2f(sh4.y), b2f(sh4.z), b2f(sh4.w)};
            float bhv[4] = {vh.x, vh.y, vh.z, vh.w};
            float o[4];
            #pragma unroll
            for (int q = 0; q < 4; ++q) {
                float pre = tanh_(acc[mi][ni][q] + pv[q] + bhv[q]);
                o[q] = (1.0f - zv[q]) * shv[q] + zv[q] * pre;
            }
            if (m == 0) { o[0] = o[1] = o[2] = o[3] = 0.0f; }
            ushort4 ov;
            ov.x = f2b(o[0]); ov.y = f2b(o[1]); ov.z = f2b(o[2]); ov.w = f2b(o[3]);
            *(ushort4*)(h + (size_t)m * 256 + col) = ov;
        }
    }
}

// out = gelu(nei@BohT^T + Pn + bo), in-place on d_out. K=256, M=20000. Grid 628.
__global__ __launch_bounds__(256) void k_mg_out(
    const u16* __restrict__ nei, const u16* __restrict__ BT,
    const float* __restrict__ bo, float* __restrict__ out) {
    __shared__ u16 As0[8192], As1[8192], Bs0[4096], Bs1[4096];
    GT_PROLOG()
    f32x4 acc[4][2]; ACC_INIT(acc)
    uint4 ra[4], rb[2];
    ldA(nei, m0, 256, 0, tid, ra); ldB(BT, n0, 256, 0, tid, rb);
    wrA(As0, tid, ra); wrB(Bs0, tid, rb);
    __syncthreads();
    ldA(nei, m0, 256, 64, tid, ra); ldB(BT, n0, 256, 64, tid, rb);
    DB_STEP(As0, Bs0, As1, Bs1, (ldA(nei, m0, 256, 128, tid, ra), ldB(BT, n0, 256, 128, tid, rb)))
    DB_STEP(As1, Bs1, As0, Bs0, (ldA(nei, m0, 256, 192, tid, ra), ldB(BT, n0, 256, 192, tid, rb)))
    DB_STEP(As0, Bs0, As1, Bs1, ;)
    mma_step(As1, Bs1, acc, lane, wr, wc);
    #pragma unroll
    for (int mi = 0; mi < 4; ++mi) {
        int m = (int)m0 + row_l + (mi << 4);
        if (m >= 20000) continue;
        #pragma unroll
        for (int ni = 0; ni < 2; ++ni) {
            int col = (int)n0 + col_l + (ni << 4);
            float4 vb = *(const float4*)(bo + col);
            const float bv[4] = {vb.x, vb.y, vb.z, vb.w};
            float o[4];
            #pragma unroll
            for (int q = 0; q < 4; ++q) {
                float pn = out[(size_t)m * 256 + col + q];
                o[q] = (m == 0) ? 0.0f : gelu_(acc[mi][ni][q] + pn + bv[q]);
            }
            #pragma unroll
            for (int q = 0; q < 4; ++q)
                out[(size_t)m * 256 + col + q] = o[q];
        }
    }
}

// ---------------------------------------------------------------------------
// sumh/sumgh gather, 2-stage pipelined loads. Grid 5000x256.
__global__ __launch_bounds__(256) void k_gather_edge(
    const u16* __restrict__ h, const u16* __restrict__ Uh,
    const u16* __restrict__ PrU, const int* __restrict__ bgraph,
    u16* __restrict__ sumh, u16* __restrict__ sumgh) {
    int e = (blockIdx.x << 3) + (threadIdx.x >> 5);
    int c = (threadIdx.x & 31) << 3;
    size_t o = (size_t)e * 256 + c;
    int bi[6];
    *(int2*)&bi[0] = *(const int2*)(bgraph + e * 6 + 0);
    *(int2*)&bi[2] = *(const int2*)(bgraph + e * 6 + 2);
    *(int2*)&bi[4] = *(const int2*)(bgraph + e * 6 + 4);
    float pr[8];
    u4tof8(*(const uint4*)(PrU + o), pr);
    float sh[8] = {}, sg[8] = {};
    uint4 hv4 = *(const uint4*)(h  + (size_t)bi[0] * 256 + c);
    uint4 uv4 = *(const uint4*)(Uh + (size_t)bi[0] * 256 + c);
    #pragma unroll
    for (int j = 0; j < 6; ++j) {
        uint4 hn, un;
        if (j < 5) {
            hn = *(const uint4*)(h  + (size_t)bi[j + 1] * 256 + c);
            un = *(const uint4*)(Uh + (size_t)bi[j + 1] * 256 + c);
        }
        float hv[8], uv[8];
        u4tof8(hv4, hv); u4tof8(uv4, uv);
        #pragma unroll
        for (int q = 0; q < 8; ++q) {
            sh[q] += hv[q];
            sg[q] += sigm(pr[q] + uv[q]) * hv[q];
        }
        hv4 = hn; uv4 = un;
    }
    *(uint4*)(sumh  + o) = f8tou4(sh);
    *(uint4*)(sumgh + o) = f8tou4(sg);
}

// nei[n] = bf16(sum_j h[agraph[n][j]]). Grid 2500x256.
__global__ __launch_bounds__(256) void k_gather_node(
    const u16* __restrict__ h, const int* __restrict__ agraph,
    u16* __restrict__ nei) {
    int n = (blockIdx.x << 3) + (threadIdx.x >> 5);
    int c = (threadIdx.x & 31) << 3;
    int ai[6];
    *(int2*)&ai[0] = *(const int2*)(agraph + n * 6 + 0);
    *(int2*)&ai[2] = *(const int2*)(agraph + n * 6 + 2);
    *(int2*)&ai[4] = *(const int2*)(agraph + n * 6 + 4);
    float s[8] = {};
    uint4 hv4 = *(const uint4*)(h + (size_t)ai[0] * 256 + c);
    #pragma unroll
    for (int j = 0; j < 6; ++j) {
        uint4 hn;
        if (j < 5) hn = *(const uint4*)(h + (size_t)ai[j + 1] * 256 + c);
        float hv[8];
        u4tof8(hv4, hv);
        #pragma unroll
        for (int q = 0; q < 8; ++q) s[q] += hv[q];
        hv4 = hn;
    }
    *(uint4*)(nei + (size_t)n * 256 + c) = f8tou4(s);
}

// ---------------------------------------------------------------------------
extern "C" void kernel_launch(void* const* d_in, const int* in_sizes, int n_in,
                              void* d_out, int out_size, void* d_ws, size_t ws_size,
                              hipStream_t stream) {
    if (ws_size < WS_BYTES) return;

    const float* fnode  = (const float*)d_in[0];
    const float* fmess  = (const float*)d_in[1];
    const int*   agraph = (const int*)d_in[2];
    const int*   bgraph = (const int*)d_in[3];
    const float* Wz  = (const float*)d_in[4];
    const float* bz  = (const float*)d_in[5];
    const float* Wr  = (const float*)d_in[6];
    const float* Ur  = (const float*)d_in[7];
    const float* urb = (const float*)d_in[8];
    const float* Wh  = (const float*)d_in[9];
    const float* bh  = (const float*)d_in[10];
    const float* Wo  = (const float*)d_in[11];
    const float* bo  = (const float*)d_in[12];

    char* base = (char*)d_ws;
    u16* PrU   = (u16*)(base + OB_PRU);
    u16* Pzx   = (u16*)(base + OB_PZX);
    u16* Phx   = (u16*)(base + OB_PHX);
    u16* h     = (u16*)(base + OB_H);
    u16* Uh    = (u16*)(base + OB_UH);
    u16* zb    = (u16*)(base + OB_UH);   // overlay: Uh dead after gather_edge
    u16* nei   = (u16*)(base + OB_UH);   // overlay: after depth loop
    u16* sumh  = (u16*)(base + OB_SH);
    u16* x     = (u16*)(base + OB_SH);   // overlay: prologue only
    u16* sumgh = (u16*)(base + OB_SGH);
    u16* fb    = (u16*)(base + OB_SGH);  // overlay: prologue only
    u16* BzxT  = (u16*)(base + OB_BZX);
    u16* BzhT  = (u16*)(base + OB_BZH);
    u16* BhxT  = (u16*)(base + OB_BHX);
    u16* BhhT  = (u16*)(base + OB_BHH);
    u16* BuT   = (u16*)(base + OB_BU);
    u16* BohT  = (u16*)(base + OB_BOH);
    u16* BrT   = (u16*)(base + OB_BR);   // prologue-only (UH overlay)
    u16* BoxT  = (u16*)(base + OB_BOX);  // prologue-only (UH overlay)
    float* out = (float*)d_out;

    hipLaunchKernelGGL(k_repack, dim3(256), dim3(256), 0, stream,
                       Wz, Wr, Ur, Wh, Wo, BzxT, BzhT, BhxT, BhhT, BuT, BohT, BrT, BoxT);
    hipLaunchKernelGGL(k_build_x, dim3(20000), dim3(256), 0, stream, fnode, fmess, x);
    hipLaunchKernelGGL(k_build_fb, dim3(10000), dim3(256), 0, stream, fnode, fb);
    hipLaunchKernelGGL(k_mg_k128, dim3(1252), dim3(256), 0, stream, x, BrT, urb, PrU);
    hipLaunchKernelGGL(k_mg_k128, dim3(1252), dim3(256), 0, stream, x, BzxT, (const float*)0, Pzx);
    hipLaunchKernelGGL(k_mg_k128, dim3(1252), dim3(256), 0, stream, x, BhxT, (const float*)0, Phx);
    hipLaunchKernelGGL(k_mg_pn, dim3(628), dim3(256), 0, stream, fb, BoxT, out);
    hipLaunchKernelGGL(k_d1, dim3(5000), dim3(256), 0, stream, Pzx, Phx, bz, bh, h);
    for (int d = 1; d < 4; ++d) {
        hipLaunchKernelGGL(k_mg_uh, dim3(1252), dim3(256), 0, stream, h, BuT, Uh);
        hipLaunchKernelGGL(k_gather_edge, dim3(5000), dim3(256), 0, stream,
                           h, Uh, PrU, bgraph, sumh, sumgh);
        hipLaunchKernelGGL(k_mg_z, dim3(1252), dim3(256), 0, stream,
                           sumh, BzhT, Pzx, bz, zb);
        hipLaunchKernelGGL(k_mg_h, dim3(1252), dim3(256), 0, stream,
                           sumgh, BhhT, Phx, bh, zb, sumh, h);
    }
    hipLaunchKernelGGL(k_gather_node, dim3(2500), dim3(256), 0, stream, h, agraph, nei);
    hipLaunchKernelGGL(k_mg_out, dim3(628), dim3(256), 0, stream, nei, BohT, bo, out);
}